// Round 4
// baseline (250.461 us; speedup 1.0000x reference)
//
#include <hip/hip_runtime.h>

#define B_ 64
#define L_ 256
#define E_ 128
#define C_ 16
#define K_ 5
#define NL_ 4
#define STEP_ 0.1f

typedef __bf16 bfh;
typedef __attribute__((ext_vector_type(8))) __bf16 bf16x8;
typedef __attribute__((ext_vector_type(4))) float f32x4;
typedef __attribute__((ext_vector_type(16))) float f32x16;

// ---------------- embedding gather -> (B,L,E) bf16 ----------------
__global__ void k_embed(const int* __restrict__ aa, const float* __restrict__ emb,
                        bfh* __restrict__ x0) {
  int i4 = blockIdx.x * 256 + threadIdx.x;
  if (i4 >= B_ * L_ * E_ / 4) return;
  int e4 = i4 & 31;
  int l = (i4 >> 5) & (L_ - 1);
  int b = i4 >> 13;
  float4 v = *(const float4*)(emb + (size_t)aa[b * L_ + l] * E_ + e4 * 4);
  union { bfh h[4]; uint2 u; } pk;
  pk.h[0] = (bfh)v.x; pk.h[1] = (bfh)v.y; pk.h[2] = (bfh)v.z; pk.h[3] = (bfh)v.w;
  *(uint2*)(x0 + (size_t)(b * L_ + l) * E_ + e4 * 4) = pk.u;
}

// ---------------- conv weights fp32 (o,i,k) -> bf16 wT[lay][k][o][i] ----------------
__global__ void k_prep_w(const float* __restrict__ w, bfh* __restrict__ wT) {
  int i = blockIdx.x * 256 + threadIdx.x;
  if (i >= NL_ * K_ * E_ * E_) return;
  int ii = i & 127;
  int rest = i >> 7;
  int o = rest & 127;
  int rest2 = rest >> 7;
  int k = rest2 % K_;
  int lay = rest2 / K_;
  wT[i] = (bfh)w[(((size_t)lay * E_ + o) * E_ + ii) * K_ + k];
}

// ---------------- t1w fp32 -> bf16 ----------------
__global__ void k_prep_t1(const float* __restrict__ t1w, bfh* __restrict__ t1wb) {
  int i = blockIdx.x * 256 + threadIdx.x;
  if (i < 2048 * 128) t1wb[i] = (bfh)t1w[i];
}

// ---------------- conv layer via MFMA ----------------
__global__ __launch_bounds__(512, 4) void k_conv(const bfh* __restrict__ xin,
                                                 const bfh* __restrict__ wT,
                                                 const float* __restrict__ bias,
                                                 bfh* __restrict__ xout) {
  __shared__ __align__(16) char hs[36 * 256];
  const int b = blockIdx.y;
  const int lb = blockIdx.x * 32;
  const int t = threadIdx.x;

  for (int s = t; s < 36 * 16; s += 512) {
    int row = s >> 4, ch = s & 15;
    int lp = lb + row - 2;
    uint4 z = {0, 0, 0, 0};
    uint4 v = (lp >= 0 && lp < L_)
                  ? *(const uint4*)(xin + ((size_t)b * L_ + lp) * E_ + ch * 8)
                  : z;
    *(uint4*)(hs + row * 256 + ((ch ^ (row & 7)) << 4)) = v;
  }
  __syncthreads();

  const int wv = t >> 6, lane = t & 63;
  const int c16 = lane & 15, kg = lane >> 4;
  const int msub = wv & 1;
  const int nq = wv >> 1;

  // hoisted biases for the two n-tiles
  const float bo0 = bias[nq * 32 + c16];
  const float bo1 = bias[nq * 32 + 16 + c16];

  bf16x8 af[K_][4];
#pragma unroll
  for (int k = 0; k < K_; ++k)
#pragma unroll
    for (int kk = 0; kk < 4; ++kk) {
      int row = msub * 16 + c16 + k;
      int ch = (kk * 4 + kg) ^ (row & 7);
      af[k][kk] = *(const bf16x8*)(hs + row * 256 + ch * 16);
    }

#pragma unroll
  for (int ntl = 0; ntl < 2; ++ntl) {
    const int n0 = nq * 32 + ntl * 16;
    f32x4 acc0 = {0.f, 0.f, 0.f, 0.f};
    f32x4 acc1 = {0.f, 0.f, 0.f, 0.f};
#pragma unroll
    for (int k = 0; k < K_; ++k) {
      const bfh* bp = wT + ((size_t)(k * E_ + n0 + c16)) * E_ + kg * 8;
      acc0 = __builtin_amdgcn_mfma_f32_16x16x32_bf16(af[k][0], *(const bf16x8*)(bp),
                                                     acc0, 0, 0, 0);
      acc1 = __builtin_amdgcn_mfma_f32_16x16x32_bf16(af[k][1], *(const bf16x8*)(bp + 32),
                                                     acc1, 0, 0, 0);
      acc0 = __builtin_amdgcn_mfma_f32_16x16x32_bf16(af[k][2], *(const bf16x8*)(bp + 64),
                                                     acc0, 0, 0, 0);
      acc1 = __builtin_amdgcn_mfma_f32_16x16x32_bf16(af[k][3], *(const bf16x8*)(bp + 96),
                                                     acc1, 0, 0, 0);
    }
    const int o = n0 + c16;
    const float bo = ntl ? bo1 : bo0;
#pragma unroll
    for (int r = 0; r < 4; ++r) {
      int lrow = msub * 16 + kg * 4 + r;
      int srow = lrow + 2;
      float res = (float)*(const bfh*)(hs + srow * 256 +
                                       (((o >> 3) ^ (srow & 7)) << 4) + (o & 7) * 2);
      float v = acc0[r] + acc1[r] + res + bo;
      float ex = __expf(2.f * v);
      float th = 1.f - 2.f / (ex + 1.f);
      xout[((size_t)b * L_ + lb + lrow) * E_ + o] = (bfh)th;
    }
  }
}

// ---------------- x2 GEMM: x2g[b][a][n] = x.t1w^T + t1b, bf16, natural layout ----------------
// grid (4, 64): 32-a block per (ablk, b). 512 thr = 8 waves (wave = nq slice of 256 n).
__global__ __launch_bounds__(512, 2) void k_x2(const bfh* __restrict__ xbg,
                                               const bfh* __restrict__ t1wb,
                                               const float* __restrict__ t1b,
                                               bfh* __restrict__ x2g,  // (B,128,2048) per pass
                                               int aBase) {
  __shared__ __align__(16) char xs[32 * 256];
  const int b = blockIdx.y;
  const int a0 = aBase + blockIdx.x * 32;
  const int apos0 = blockIdx.x * 32;  // within-pass a index
  const int t = threadIdx.x;

  {
    int row = t >> 4, ch = t & 15;
    uint4 v = *(const uint4*)(xbg + ((size_t)b * L_ + a0 + row) * E_ + ch * 8);
    *(uint4*)(xs + row * 256 + ((ch ^ (row & 7)) << 4)) = v;
  }
  __syncthreads();

  const int wv = t >> 6, lane = t & 63;
  const int l31 = lane & 31, hi = lane >> 5;

  bf16x8 af[8];
#pragma unroll
  for (int kk = 0; kk < 8; ++kk)
    af[kk] = *(const bf16x8*)(xs + l31 * 256 + (((kk * 2 + hi) ^ (l31 & 7)) << 4));

#pragma unroll 1
  for (int nt = 0; nt < 8; ++nt) {
    const int n0 = wv * 256 + nt * 32;
    const bfh* bp = t1wb + (size_t)(n0 + l31) * E_ + hi * 8;
    f32x16 acc0, acc1;
#pragma unroll
    for (int q = 0; q < 16; ++q) { acc0[q] = 0.f; acc1[q] = 0.f; }
    acc0 = __builtin_amdgcn_mfma_f32_32x32x16_bf16(af[0], *(const bf16x8*)(bp), acc0, 0, 0, 0);
    acc1 = __builtin_amdgcn_mfma_f32_32x32x16_bf16(af[1], *(const bf16x8*)(bp + 16), acc1, 0, 0, 0);
    acc0 = __builtin_amdgcn_mfma_f32_32x32x16_bf16(af[2], *(const bf16x8*)(bp + 32), acc0, 0, 0, 0);
    acc1 = __builtin_amdgcn_mfma_f32_32x32x16_bf16(af[3], *(const bf16x8*)(bp + 48), acc1, 0, 0, 0);
    acc0 = __builtin_amdgcn_mfma_f32_32x32x16_bf16(af[4], *(const bf16x8*)(bp + 64), acc0, 0, 0, 0);
    acc1 = __builtin_amdgcn_mfma_f32_32x32x16_bf16(af[5], *(const bf16x8*)(bp + 80), acc1, 0, 0, 0);
    acc0 = __builtin_amdgcn_mfma_f32_32x32x16_bf16(af[6], *(const bf16x8*)(bp + 96), acc0, 0, 0, 0);
    acc1 = __builtin_amdgcn_mfma_f32_32x32x16_bf16(af[7], *(const bf16x8*)(bp + 112), acc1, 0, 0, 0);
    const float bv = t1b[n0 + l31];
#pragma unroll
    for (int q = 0; q < 16; ++q) {
      int a_loc = (q & 3) + 8 * (q >> 2) + 4 * hi;
      x2g[((size_t)(b * 128 + apos0 + a_loc)) * 2048 + n0 + l31] =
          (bfh)(acc0[q] + acc1[q] + bv);
    }
  }
}

// ---------------- pairwise kernel: scores + softmax + accumulate + vd ----------------
#define RELAY 0        // 16 KB: [16 a][512 n] bf16 chunk of x2g
#define BBS2 16384     // 3 KB
#define RED2 19456     // 4 KB: [16 a][16 c][4 m] f32
#define PSMEM 23552

__global__ __launch_bounds__(512, 4) void k_pair(
    const bfh* __restrict__ xbg,    // (B,L,E) bf16
    const float* __restrict__ bb,   // (B,L,3)
    const bfh* __restrict__ x2g,    // (B,128,2048) bf16, this pass
    const float* __restrict__ t2w,
    const float* __restrict__ t2b,
    float* __restrict__ nbb,
    int aBase) {
  __shared__ __align__(16) char smem[PSMEM];
  const int t = threadIdx.x;
  const int b = blockIdx.x >> 3;
  const int atile = blockIdx.x & 7;
  const int a0 = aBase + atile * 16;
  const int lane = t & 63;
  const int wv = t >> 6;
  const int l31 = lane & 31;
  const int hi = lane >> 5;

  float* bbs = (float*)(smem + BBS2);
  if (t < 192) ((float4*)bbs)[t] = ((const float4*)(bb + b * (L_ * 3)))[t];

  // ---- build A-frags from x2g via 16KB relay (one-time) ----
  bf16x8 afr[8];
  char* rel = smem + RELAY;
  const int alsb = (l31 >> 2) & 1;
  const int cdec = (l31 & 3) | ((l31 >> 3) << 2);
  const int arow = wv * 2 + alsb;
#pragma unroll 1
  for (int ch = 0; ch < 4; ++ch) {
    if (ch > 0) __syncthreads();
#pragma unroll
    for (int i = 0; i < 2; ++i) {
      int s = t + i * 512;
      int row = s >> 6, cc = s & 63;
      *(uint4*)(rel + row * 1024 + cc * 16) =
          *(const uint4*)(x2g + ((size_t)(b * 128 + atile * 16 + row)) * 2048 +
                          ch * 512 + cc * 8);
    }
    __syncthreads();
#pragma unroll
    for (int kx = 0; kx < 2; ++kx) {
      union { ushort u[8]; bf16x8 v; } fr;
#pragma unroll
      for (int j = 0; j < 8; ++j) {
        int eloc = kx * 16 + hi * 8 + j;
        fr.u[j] = *(const ushort*)(rel + arow * 1024 + (eloc * 16 + cdec) * 2);
      }
      afr[ch * 2 + kx] = fr.v;
    }
  }

  // ---- main d-loop: no barriers, no LDS staging ----
  const int aglob = a0 + 2 * wv + hi;
  const float bax0 = bbs[aglob * 3 + 0];
  const float bax1 = bbs[aglob * 3 + 1];
  const float bax2 = bbs[aglob * 3 + 2];

  float accX[16], accY[16], accZ[16], accS[16];
#pragma unroll
  for (int q = 0; q < 16; ++q) { accX[q] = 0.f; accY[q] = 0.f; accZ[q] = 0.f; accS[q] = 0.f; }

#pragma unroll 1
  for (int dt = 0; dt < 8; ++dt) {
    const bfh* xp = xbg + ((size_t)b * L_ + dt * 32 + l31) * E_ + hi * 8;
    f32x16 acc;
#pragma unroll
    for (int q = 0; q < 16; ++q) acc[q] = 0.f;
#pragma unroll
    for (int kk = 0; kk < 8; ++kk)
      acc = __builtin_amdgcn_mfma_f32_32x32x16_bf16(afr[kk], *(const bf16x8*)(xp + kk * 16),
                                                    acc, 0, 0, 0);
    const int d = dt * 32 + l31;
    const float dx = bax0 - bbs[d * 3 + 0];
    const float dy = bax1 - bbs[d * 3 + 1];
    const float dz = bax2 - bbs[d * 3 + 2];
    float mx = acc[0];
#pragma unroll
    for (int q = 1; q < 16; ++q) mx = fmaxf(mx, acc[q]);
    float p[16], S = 0.f;
#pragma unroll
    for (int q = 0; q < 16; ++q) { p[q] = __expf(acc[q] - mx); S += p[q]; }
    const float inv = __builtin_amdgcn_rcpf(S);
#pragma unroll
    for (int q = 0; q < 16; ++q) {
      const float u = p[q] * inv;
      accS[q] += u;
      accX[q] = fmaf(u, dx, accX[q]);
      accY[q] = fmaf(u, dy, accY[q]);
      accZ[q] = fmaf(u, dz, accZ[q]);
    }
  }

  // ---- halving-butterfly reduction over the 32 d-lanes ----
  float v64[64];
#pragma unroll
  for (int c = 0; c < 16; ++c) {
    v64[c * 4 + 0] = accX[c];
    v64[c * 4 + 1] = accY[c];
    v64[c * 4 + 2] = accZ[c];
    v64[c * 4 + 3] = accS[c];
  }
  float v32[32], v16a[16], v8[8], v4[4], v2[2];
  {
    const int bit = l31 & 1;
#pragma unroll
    for (int i = 0; i < 32; ++i) {
      float keep = bit ? v64[i + 32] : v64[i];
      float send = bit ? v64[i] : v64[i + 32];
      v32[i] = keep + __shfl_xor(send, 1);
    }
  }
  {
    const int bit = (l31 >> 1) & 1;
#pragma unroll
    for (int i = 0; i < 16; ++i) {
      float keep = bit ? v32[i + 16] : v32[i];
      float send = bit ? v32[i] : v32[i + 16];
      v16a[i] = keep + __shfl_xor(send, 2);
    }
  }
  {
    const int bit = (l31 >> 2) & 1;
#pragma unroll
    for (int i = 0; i < 8; ++i) {
      float keep = bit ? v16a[i + 8] : v16a[i];
      float send = bit ? v16a[i] : v16a[i + 8];
      v8[i] = keep + __shfl_xor(send, 4);
    }
  }
  {
    const int bit = (l31 >> 3) & 1;
#pragma unroll
    for (int i = 0; i < 4; ++i) {
      float keep = bit ? v8[i + 4] : v8[i];
      float send = bit ? v8[i] : v8[i + 4];
      v4[i] = keep + __shfl_xor(send, 8);
    }
  }
  {
    const int bit = (l31 >> 4) & 1;
#pragma unroll
    for (int i = 0; i < 2; ++i) {
      float keep = bit ? v4[i + 2] : v4[i];
      float send = bit ? v4[i] : v4[i + 2];
      v2[i] = keep + __shfl_xor(send, 16);
    }
  }
  float* red = (float*)(smem + RED2);
  {
    const int q0 = ((l31 & 1) << 5) | (((l31 >> 1) & 1) << 4) | (((l31 >> 2) & 1) << 3) |
                   (((l31 >> 3) & 1) << 2) | (((l31 >> 4) & 1) << 1);
    const int a_loc = 2 * wv + hi;
    red[a_loc * 64 + q0] = v2[0];
    red[a_loc * 64 + q0 + 1] = v2[1];
  }
  __syncthreads();

  // ---- vd and new_bb ----
  if (t < 48) {
    int a = t / 3, k = t % 3;
    float vd = 0.f;
#pragma unroll
    for (int c = 0; c < C_; ++c) {
      const float* w2 = t2w + (k * C_ + c) * 3;
      const float* rr = red + a * 64 + c * 4;
      vd += w2[0] * rr[0] + w2[1] * rr[1] + w2[2] * rr[2] + t2b[k * C_ + c] * rr[3];
    }
    nbb[(size_t)(b * L_ + a0 + a) * 3 + k] = bbs[(a0 + a) * 3 + k] + STEP_ * vd;
  }
}

// ---------------- mse over frames ----------------
__global__ void k_mse(const float* __restrict__ nbb, const float* __restrict__ bb,
                      float* __restrict__ out) {
  const int b = blockIdx.x;
  const int t = threadIdx.x;
  const float* pn = nbb + ((b + 1) * L_ + t) * 3;
  const float* pb = bb + (b * L_ + t) * 3;
  const float dx = pn[0] - pb[0];
  const float dy = pn[1] - pb[1];
  const float dz = pn[2] - pb[2];
  float v = dx * dx + dy * dy + dz * dz;
  for (int o = 32; o > 0; o >>= 1) v += __shfl_down(v, o);
  __shared__ float wsum[4];
  if ((t & 63) == 0) wsum[t >> 6] = v;
  __syncthreads();
  if (t == 0) out[b] = (wsum[0] + wsum[1] + wsum[2] + wsum[3]) * (1.0f / L_);
}

extern "C" void kernel_launch(void* const* d_in, const int* in_sizes, int n_in,
                              void* d_out, int out_size, void* d_ws, size_t ws_size,
                              hipStream_t stream) {
  const int* aa = (const int*)d_in[0];
  const float* bb = (const float*)d_in[1];
  const float* emb = (const float*)d_in[2];
  const float* conv_w = (const float*)d_in[3];
  const float* conv_b = (const float*)d_in[4];
  const float* t1w = (const float*)d_in[5];
  const float* t1b = (const float*)d_in[6];
  const float* t2w = (const float*)d_in[7];
  const float* t2b = (const float*)d_in[8];
  float* out = (float*)d_out;

  char* ws = (char*)d_ws;
  bfh* xA = (bfh*)ws;                          // 4 MB
  bfh* xB = (bfh*)(ws + 4194304);              // 4 MB
  bfh* t1wb = (bfh*)(ws + 8388608);            // 512 KB
  bfh* wT = (bfh*)(ws + 8912896);              // 640 KB
  float* nbb = (float*)(ws + 9568256);         // 192 KB
  bfh* x2g = (bfh*)(ws + 10485760);            // 32 MB (per-pass)

  k_prep_t1<<<1024, 256, 0, stream>>>(t1w, t1wb);
  k_prep_w<<<(NL_ * K_ * E_ * E_ + 255) / 256, 256, 0, stream>>>(conv_w, wT);
  k_embed<<<B_ * L_ * E_ / 4 / 256, 256, 0, stream>>>(aa, emb, xA);

  for (int i = 0; i < NL_; ++i) {
    const bfh* src = (i & 1) ? xB : xA;
    bfh* dst = (i & 1) ? xA : xB;
    k_conv<<<dim3(L_ / 32, B_), 512, 0, stream>>>(src, wT + (size_t)i * K_ * E_ * E_,
                                                  conv_b + i * E_, dst);
  }
  // final features in xA

  for (int pass = 0; pass < 2; ++pass) {
    const int aBase = pass * 128;
    k_x2<<<dim3(4, B_), 512, 0, stream>>>(xA, t1wb, t1b, x2g, aBase);
    k_pair<<<B_ * 8, 512, 0, stream>>>(xA, bb, x2g, t2w, t2b, nbb, aBase);
  }

  k_mse<<<B_ - 1, 256, 0, stream>>>(nbb, bb, out);
}

// Round 5
// 236.132 us; speedup vs baseline: 1.0607x; 1.0607x over previous
//
#include <hip/hip_runtime.h>

#define B_ 64
#define L_ 256
#define E_ 128
#define C_ 16
#define K_ 5
#define NL_ 4
#define STEP_ 0.1f

typedef __bf16 bfh;
typedef __attribute__((ext_vector_type(8))) __bf16 bf16x8;
typedef __attribute__((ext_vector_type(4))) float f32x4;
typedef __attribute__((ext_vector_type(16))) float f32x16;

// ---------------- embedding gather -> (B,L,E) bf16 ----------------
__global__ void k_embed(const int* __restrict__ aa, const float* __restrict__ emb,
                        bfh* __restrict__ x0) {
  int i4 = blockIdx.x * 256 + threadIdx.x;
  if (i4 >= B_ * L_ * E_ / 4) return;
  int e4 = i4 & 31;
  int l = (i4 >> 5) & (L_ - 1);
  int b = i4 >> 13;
  float4 v = *(const float4*)(emb + (size_t)aa[b * L_ + l] * E_ + e4 * 4);
  union { bfh h[4]; uint2 u; } pk;
  pk.h[0] = (bfh)v.x; pk.h[1] = (bfh)v.y; pk.h[2] = (bfh)v.z; pk.h[3] = (bfh)v.w;
  *(uint2*)(x0 + (size_t)(b * L_ + l) * E_ + e4 * 4) = pk.u;
}

// ---------------- conv weights fp32 (o,i,k) -> bf16 wT[lay][k][o][i] ----------------
__global__ void k_prep_w(const float* __restrict__ w, bfh* __restrict__ wT) {
  int i = blockIdx.x * 256 + threadIdx.x;
  if (i >= NL_ * K_ * E_ * E_) return;
  int ii = i & 127;
  int rest = i >> 7;
  int o = rest & 127;
  int rest2 = rest >> 7;
  int k = rest2 % K_;
  int lay = rest2 / K_;
  wT[i] = (bfh)w[(((size_t)lay * E_ + o) * E_ + ii) * K_ + k];
}

// ---------------- t1w fp32 -> bf16 ----------------
__global__ void k_prep_t1(const float* __restrict__ t1w, bfh* __restrict__ t1wb) {
  int i = blockIdx.x * 256 + threadIdx.x;
  if (i < 2048 * 128) t1wb[i] = (bfh)t1w[i];
}

// ---------------- conv layer via MFMA (low-VGPR variant) ----------------
__global__ __launch_bounds__(512, 4) void k_conv(const bfh* __restrict__ xin,
                                                 const bfh* __restrict__ wT,
                                                 const float* __restrict__ bias,
                                                 bfh* __restrict__ xout) {
  __shared__ __align__(16) char hs[36 * 256];
  const int b = blockIdx.y;
  const int lb = blockIdx.x * 32;
  const int t = threadIdx.x;

  for (int s = t; s < 36 * 16; s += 512) {
    int row = s >> 4, ch = s & 15;
    int lp = lb + row - 2;
    uint4 z = {0, 0, 0, 0};
    uint4 v = (lp >= 0 && lp < L_)
                  ? *(const uint4*)(xin + ((size_t)b * L_ + lp) * E_ + ch * 8)
                  : z;
    *(uint4*)(hs + row * 256 + ((ch ^ (row & 7)) << 4)) = v;
  }
  __syncthreads();

  const int wv = t >> 6, lane = t & 63;
  const int c16 = lane & 15, kg = lane >> 4;
  const int msub = wv & 1;
  const int nq = wv >> 1;

#pragma unroll
  for (int ntl = 0; ntl < 2; ++ntl) {
    const int n0 = nq * 32 + ntl * 16;
    f32x4 acc = {0.f, 0.f, 0.f, 0.f};
#pragma unroll
    for (int k = 0; k < K_; ++k) {
      const bfh* bp = wT + ((size_t)(k * E_ + n0 + c16)) * E_ + kg * 8;
      bf16x8 b0 = *(const bf16x8*)(bp);
      bf16x8 b1 = *(const bf16x8*)(bp + 32);
      bf16x8 b2 = *(const bf16x8*)(bp + 64);
      bf16x8 b3 = *(const bf16x8*)(bp + 96);
      const int row = msub * 16 + c16 + k;
      bf16x8 a0 = *(const bf16x8*)(hs + row * 256 + (((0 * 4 + kg) ^ (row & 7)) << 4));
      bf16x8 a1 = *(const bf16x8*)(hs + row * 256 + (((1 * 4 + kg) ^ (row & 7)) << 4));
      bf16x8 a2 = *(const bf16x8*)(hs + row * 256 + (((2 * 4 + kg) ^ (row & 7)) << 4));
      bf16x8 a3 = *(const bf16x8*)(hs + row * 256 + (((3 * 4 + kg) ^ (row & 7)) << 4));
      acc = __builtin_amdgcn_mfma_f32_16x16x32_bf16(a0, b0, acc, 0, 0, 0);
      acc = __builtin_amdgcn_mfma_f32_16x16x32_bf16(a1, b1, acc, 0, 0, 0);
      acc = __builtin_amdgcn_mfma_f32_16x16x32_bf16(a2, b2, acc, 0, 0, 0);
      acc = __builtin_amdgcn_mfma_f32_16x16x32_bf16(a3, b3, acc, 0, 0, 0);
    }
    const int o = n0 + c16;
    const float bo = bias[o];
#pragma unroll
    for (int r = 0; r < 4; ++r) {
      int lrow = msub * 16 + kg * 4 + r;
      int srow = lrow + 2;
      float res = (float)*(const bfh*)(hs + srow * 256 +
                                       (((o >> 3) ^ (srow & 7)) << 4) + (o & 7) * 2);
      float v = acc[r] + res + bo;
      float ex = __expf(2.f * v);
      float th = 1.f - 2.f / (ex + 1.f);
      xout[((size_t)b * L_ + lb + lrow) * E_ + o] = (bfh)th;
    }
  }
}

// ---------------- fused kernel: x2 GEMM + scores + softmax + accumulate + vd ----------------
#define X2S 0            // 64 KB: 256 rows x 256B swizzled (aliased as scr f32 in reduce)
#define XAS 65536        //  4 KB: 16 rows x 256B swizzled
#define BBS 69632        //  3 KB
#define RED 72704        //  4 KB: [16 a][64] f32
#define SMEM_SZ 76800

__global__ __launch_bounds__(512, 2) void k_all(
    const bfh* __restrict__ xbg,    // (B,L,E) bf16
    const float* __restrict__ bb,   // (B,L,3)
    const bfh* __restrict__ t1wb,   // (2048,128) bf16
    const float* __restrict__ t1b,  // (2048)
    const float* __restrict__ t2w,
    const float* __restrict__ t2b,
    float* __restrict__ nbb) {
  __shared__ __align__(16) char smem[SMEM_SZ];
  const int t = threadIdx.x;
  const unsigned u = blockIdx.x;
  const int b = (u & 7) | ((u >> 7) << 3);   // XCD-affine: all 16 tiles of b on one XCD
  const int a0 = ((u >> 3) & 15) << 4;
  const int lane = t & 63;
  const int wv = t >> 6;
  const int c16 = lane & 15;
  const int kg = lane >> 4;
  const int l31 = lane & 31;
  const int hi = lane >> 5;

  float* bbs = (float*)(smem + BBS);
  if (t < 192) ((float4*)bbs)[t] = ((const float4*)(bb + b * (L_ * 3)))[t];
  if (t < 256) {
    int row = t >> 4, ch = t & 15;
    uint4 v = *(const uint4*)(xbg + ((size_t)b * L_ + a0 + row) * E_ + ch * 8);
    *(uint4*)(smem + XAS + row * 256 + ((ch ^ (row & 7)) << 4)) = v;
  }
  __syncthreads();

  // ---- phase 1: x2 tile via 16x16x32, B prefetched from global ----
  {
    bf16x8 a1[4];
#pragma unroll
    for (int kk = 0; kk < 4; ++kk)
      a1[kk] = *(const bf16x8*)(smem + XAS + c16 * 256 +
                                (((kk * 4 + kg) ^ (c16 & 7)) << 4));
    const int ntB = wv * 16;
    bf16x8 cur[4], nxt[4];
    {
      const bfh* bsrc = t1wb + (size_t)(ntB * 16 + c16) * E_ + kg * 8;
#pragma unroll
      for (int kk = 0; kk < 4; ++kk) cur[kk] = *(const bf16x8*)(bsrc + kk * 32);
    }
#pragma unroll
    for (int i = 0; i < 16; ++i) {
      const int nt = ntB + i;
      if (i < 15) {
        const bfh* bsrc = t1wb + (size_t)((nt + 1) * 16 + c16) * E_ + kg * 8;
#pragma unroll
        for (int kk = 0; kk < 4; ++kk) nxt[kk] = *(const bf16x8*)(bsrc + kk * 32);
      }
      f32x4 acc = {0.f, 0.f, 0.f, 0.f};
#pragma unroll
      for (int kk = 0; kk < 4; ++kk)
        acc = __builtin_amdgcn_mfma_f32_16x16x32_bf16(a1[kk], cur[kk], acc, 0, 0, 0);
      const float bias = t1b[nt * 16 + c16];
#pragma unroll
      for (int r = 0; r < 4; ++r) {
        int a = kg * 4 + r;
        int row = (a >> 1) * 32 + ((c16 & 3) | ((a & 1) << 2) | ((c16 >> 2) << 3));
        *(bfh*)(smem + X2S + row * 256 + (((nt >> 3) ^ (row & 7)) << 4) + (nt & 7) * 2) =
            (bfh)(acc[r] + bias);
      }
#pragma unroll
      for (int kk = 0; kk < 4; ++kk) cur[kk] = nxt[kk];
    }
  }
  __syncthreads();

  // ---- phase 2: scores via 32x32x16, B-frags direct from global, no barriers ----
  bf16x8 afr[8];
#pragma unroll
  for (int kk = 0; kk < 8; ++kk) {
    int row = wv * 32 + l31;
    afr[kk] = *(const bf16x8*)(smem + X2S + row * 256 + (((kk * 2 + hi) ^ (l31 & 7)) << 4));
  }
  const int aglob = a0 + 2 * wv + hi;
  const float bax0 = bbs[aglob * 3 + 0];
  const float bax1 = bbs[aglob * 3 + 1];
  const float bax2 = bbs[aglob * 3 + 2];

  float accX[16], accY[16], accZ[16], accS[16];
#pragma unroll
  for (int q = 0; q < 16; ++q) { accX[q] = 0.f; accY[q] = 0.f; accZ[q] = 0.f; accS[q] = 0.f; }

  bf16x8 bcur[8], bnxt[8];
  {
    const bfh* xp = xbg + ((size_t)b * L_ + l31) * E_ + hi * 8;
#pragma unroll
    for (int kk = 0; kk < 8; ++kk) bcur[kk] = *(const bf16x8*)(xp + kk * 16);
  }
#pragma unroll
  for (int dt = 0; dt < 8; ++dt) {
    if (dt < 7) {
      const bfh* xp = xbg + ((size_t)b * L_ + (dt + 1) * 32 + l31) * E_ + hi * 8;
#pragma unroll
      for (int kk = 0; kk < 8; ++kk) bnxt[kk] = *(const bf16x8*)(xp + kk * 16);
    }
    f32x16 acc;
#pragma unroll
    for (int q = 0; q < 16; ++q) acc[q] = 0.f;
#pragma unroll
    for (int kk = 0; kk < 8; ++kk)
      acc = __builtin_amdgcn_mfma_f32_32x32x16_bf16(afr[kk], bcur[kk], acc, 0, 0, 0);
    const int d = dt * 32 + l31;
    const float dx = bax0 - bbs[d * 3 + 0];
    const float dy = bax1 - bbs[d * 3 + 1];
    const float dz = bax2 - bbs[d * 3 + 2];
    float mx = acc[0];
#pragma unroll
    for (int q = 1; q < 16; ++q) mx = fmaxf(mx, acc[q]);
    float p[16], S = 0.f;
#pragma unroll
    for (int q = 0; q < 16; ++q) { p[q] = __expf(acc[q] - mx); S += p[q]; }
    const float inv = __builtin_amdgcn_rcpf(S);
#pragma unroll
    for (int q = 0; q < 16; ++q) {
      const float uu = p[q] * inv;
      accS[q] += uu;
      accX[q] = fmaf(uu, dx, accX[q]);
      accY[q] = fmaf(uu, dy, accY[q]);
      accZ[q] = fmaf(uu, dz, accZ[q]);
    }
#pragma unroll
    for (int kk = 0; kk < 8; ++kk) bcur[kk] = bnxt[kk];
  }

  // ---- phase 3: reduce 32 d-lanes via LDS transpose (X2S dead -> scr) ----
  float* scr = (float*)smem;
  float* red = (float*)(smem + RED);
#pragma unroll
  for (int pass = 0; pass < 2; ++pass) {
    __syncthreads();
#pragma unroll
    for (int c2 = 0; c2 < 8; ++c2) {
      int c = pass * 8 + c2;
      int base = ((wv * 2 + hi) * 8 + c2) * 4;
      scr[(base + 0) * 32 + l31] = accX[c];
      scr[(base + 1) * 32 + l31] = accY[c];
      scr[(base + 2) * 32 + l31] = accZ[c];
      scr[(base + 3) * 32 + l31] = accS[c];
    }
    __syncthreads();
    {
      float v = 0.f;
#pragma unroll
      for (int j = 0; j < 32; ++j) v += scr[t * 32 + ((j + t) & 31)];
      int m = t & 3, c2 = (t >> 2) & 7, hh = (t >> 5) & 1, wp = t >> 6;
      red[((wp * 2 + hh) * 16 + pass * 8 + c2) * 4 + m] = v;
    }
  }
  __syncthreads();

  // ---- phase 4: vd and new_bb ----
  if (t < 48) {
    int a = t / 3, k = t % 3;
    float vd = 0.f;
#pragma unroll
    for (int c = 0; c < C_; ++c) {
      const float* w2 = t2w + (k * C_ + c) * 3;
      const float* rr = red + (a * 16 + c) * 4;
      vd += w2[0] * rr[0] + w2[1] * rr[1] + w2[2] * rr[2] + t2b[k * C_ + c] * rr[3];
    }
    nbb[(size_t)(b * L_ + a0 + a) * 3 + k] = bbs[(a0 + a) * 3 + k] + STEP_ * vd;
  }
}

// ---------------- mse over frames ----------------
__global__ void k_mse(const float* __restrict__ nbb, const float* __restrict__ bb,
                      float* __restrict__ out) {
  const int b = blockIdx.x;
  const int t = threadIdx.x;
  const float* pn = nbb + ((b + 1) * L_ + t) * 3;
  const float* pb = bb + (b * L_ + t) * 3;
  const float dx = pn[0] - pb[0];
  const float dy = pn[1] - pb[1];
  const float dz = pn[2] - pb[2];
  float v = dx * dx + dy * dy + dz * dz;
  for (int o = 32; o > 0; o >>= 1) v += __shfl_down(v, o);
  __shared__ float wsum[4];
  if ((t & 63) == 0) wsum[t >> 6] = v;
  __syncthreads();
  if (t == 0) out[b] = (wsum[0] + wsum[1] + wsum[2] + wsum[3]) * (1.0f / L_);
}

extern "C" void kernel_launch(void* const* d_in, const int* in_sizes, int n_in,
                              void* d_out, int out_size, void* d_ws, size_t ws_size,
                              hipStream_t stream) {
  const int* aa = (const int*)d_in[0];
  const float* bb = (const float*)d_in[1];
  const float* emb = (const float*)d_in[2];
  const float* conv_w = (const float*)d_in[3];
  const float* conv_b = (const float*)d_in[4];
  const float* t1w = (const float*)d_in[5];
  const float* t1b = (const float*)d_in[6];
  const float* t2w = (const float*)d_in[7];
  const float* t2b = (const float*)d_in[8];
  float* out = (float*)d_out;

  char* ws = (char*)d_ws;
  bfh* xA = (bfh*)ws;                          // 4 MB
  bfh* xB = (bfh*)(ws + 4194304);              // 4 MB
  bfh* t1wb = (bfh*)(ws + 8388608);            // 512 KB
  bfh* wT = (bfh*)(ws + 8912896);              // 640 KB
  float* nbb = (float*)(ws + 9568256);         // 192 KB

  k_prep_t1<<<1024, 256, 0, stream>>>(t1w, t1wb);
  k_prep_w<<<(NL_ * K_ * E_ * E_ + 255) / 256, 256, 0, stream>>>(conv_w, wT);
  k_embed<<<B_ * L_ * E_ / 4 / 256, 256, 0, stream>>>(aa, emb, xA);

  for (int i = 0; i < NL_; ++i) {
    const bfh* src = (i & 1) ? xB : xA;
    bfh* dst = (i & 1) ? xA : xB;
    k_conv<<<dim3(L_ / 32, B_), 512, 0, stream>>>(src, wT + (size_t)i * K_ * E_ * E_,
                                                  conv_b + i * E_, dst);
  }

  k_all<<<B_ * 16, 512, 0, stream>>>(xA, bb, t1wb, t1b, t2w, t2b, nbb);

  k_mse<<<B_ - 1, 256, 0, stream>>>(nbb, bb, out);
}

// Round 6
// 198.236 us; speedup vs baseline: 1.2634x; 1.1912x over previous
//
#include <hip/hip_runtime.h>

#define B_ 64
#define L_ 256
#define E_ 128
#define C_ 16
#define K_ 5
#define NL_ 4
#define STEP_ 0.1f

typedef __bf16 bfh;
typedef __attribute__((ext_vector_type(8))) __bf16 bf16x8;
typedef __attribute__((ext_vector_type(4))) float f32x4;
typedef __attribute__((ext_vector_type(16))) float f32x16;

#define SWZ(r) (((r) ^ ((r) >> 4)) & 15)

// ---------------- embedding gather -> (B,L,E) bf16 ----------------
__global__ void k_embed(const int* __restrict__ aa, const float* __restrict__ emb,
                        bfh* __restrict__ x0) {
  int i4 = blockIdx.x * 256 + threadIdx.x;
  if (i4 >= B_ * L_ * E_ / 4) return;
  int e4 = i4 & 31;
  int l = (i4 >> 5) & (L_ - 1);
  int b = i4 >> 13;
  float4 v = *(const float4*)(emb + (size_t)aa[b * L_ + l] * E_ + e4 * 4);
  union { bfh h[4]; uint2 u; } pk;
  pk.h[0] = (bfh)v.x; pk.h[1] = (bfh)v.y; pk.h[2] = (bfh)v.z; pk.h[3] = (bfh)v.w;
  *(uint2*)(x0 + (size_t)(b * L_ + l) * E_ + e4 * 4) = pk.u;
}

// ---------------- conv weights fp32 (o,i,k) -> bf16 wT[lay][k][o][i] ----------------
__global__ void k_prep_w(const float* __restrict__ w, bfh* __restrict__ wT) {
  int i = blockIdx.x * 256 + threadIdx.x;
  if (i >= NL_ * K_ * E_ * E_) return;
  int ii = i & 127;
  int rest = i >> 7;
  int o = rest & 127;
  int rest2 = rest >> 7;
  int k = rest2 % K_;
  int lay = rest2 / K_;
  wT[i] = (bfh)w[(((size_t)lay * E_ + o) * E_ + ii) * K_ + k];
}

// ---------------- t1w fp32 -> bf16 ----------------
__global__ void k_prep_t1(const float* __restrict__ t1w, bfh* __restrict__ t1wb) {
  int i = blockIdx.x * 256 + threadIdx.x;
  if (i < 2048 * 128) t1wb[i] = (bfh)t1w[i];
}

// ---------------- conv layer via MFMA (low-VGPR variant) ----------------
__global__ __launch_bounds__(512, 4) void k_conv(const bfh* __restrict__ xin,
                                                 const bfh* __restrict__ wT,
                                                 const float* __restrict__ bias,
                                                 bfh* __restrict__ xout) {
  __shared__ __align__(16) char hs[36 * 256];
  const int b = blockIdx.y;
  const int lb = blockIdx.x * 32;
  const int t = threadIdx.x;

  for (int s = t; s < 36 * 16; s += 512) {
    int row = s >> 4, ch = s & 15;
    int lp = lb + row - 2;
    uint4 z = {0, 0, 0, 0};
    uint4 v = (lp >= 0 && lp < L_)
                  ? *(const uint4*)(xin + ((size_t)b * L_ + lp) * E_ + ch * 8)
                  : z;
    *(uint4*)(hs + row * 256 + ((ch ^ (row & 7)) << 4)) = v;
  }
  __syncthreads();

  const int wv = t >> 6, lane = t & 63;
  const int c16 = lane & 15, kg = lane >> 4;
  const int msub = wv & 1;
  const int nq = wv >> 1;

#pragma unroll
  for (int ntl = 0; ntl < 2; ++ntl) {
    const int n0 = nq * 32 + ntl * 16;
    f32x4 acc = {0.f, 0.f, 0.f, 0.f};
#pragma unroll
    for (int k = 0; k < K_; ++k) {
      const bfh* bp = wT + ((size_t)(k * E_ + n0 + c16)) * E_ + kg * 8;
      bf16x8 b0 = *(const bf16x8*)(bp);
      bf16x8 b1 = *(const bf16x8*)(bp + 32);
      bf16x8 b2 = *(const bf16x8*)(bp + 64);
      bf16x8 b3 = *(const bf16x8*)(bp + 96);
      const int row = msub * 16 + c16 + k;
      bf16x8 a0 = *(const bf16x8*)(hs + row * 256 + (((0 * 4 + kg) ^ (row & 7)) << 4));
      bf16x8 a1 = *(const bf16x8*)(hs + row * 256 + (((1 * 4 + kg) ^ (row & 7)) << 4));
      bf16x8 a2 = *(const bf16x8*)(hs + row * 256 + (((2 * 4 + kg) ^ (row & 7)) << 4));
      bf16x8 a3 = *(const bf16x8*)(hs + row * 256 + (((3 * 4 + kg) ^ (row & 7)) << 4));
      acc = __builtin_amdgcn_mfma_f32_16x16x32_bf16(a0, b0, acc, 0, 0, 0);
      acc = __builtin_amdgcn_mfma_f32_16x16x32_bf16(a1, b1, acc, 0, 0, 0);
      acc = __builtin_amdgcn_mfma_f32_16x16x32_bf16(a2, b2, acc, 0, 0, 0);
      acc = __builtin_amdgcn_mfma_f32_16x16x32_bf16(a3, b3, acc, 0, 0, 0);
    }
    const int o = n0 + c16;
    const float bo = bias[o];
#pragma unroll
    for (int r = 0; r < 4; ++r) {
      int lrow = msub * 16 + kg * 4 + r;
      int srow = lrow + 2;
      float res = (float)*(const bfh*)(hs + srow * 256 +
                                       (((o >> 3) ^ (srow & 7)) << 4) + (o & 7) * 2);
      float v = acc[r] + res + bo;
      float ex = __expf(2.f * v);
      float th = 1.f - 2.f / (ex + 1.f);
      xout[((size_t)b * L_ + lb + lrow) * E_ + o] = (bfh)th;
    }
  }
}

// ---------------- fused kernel: x2 GEMM + scores + softmax + accumulate + vd ----------------
// XBIG: phase1 = x2 tile (256 rows x 256B); phase2 = staged x frame (256 d-rows);
//       phase3 = scr (f32 transpose scratch). All swizzled with SWZ(row).
#define XBIG 0           // 64 KB
#define XAS 65536        //  4 KB: 16 rows x 256B (phase-1 A tile)
#define BBS 69632        //  3 KB
#define RED 72704        //  4 KB: [16 a][16 c][4 m] f32
#define SMEM_SZ 76800

__global__ __launch_bounds__(512, 2) void k_all(
    const bfh* __restrict__ xbg,    // (B,L,E) bf16
    const float* __restrict__ bb,   // (B,L,3)
    const bfh* __restrict__ t1wb,   // (2048,128) bf16
    const float* __restrict__ t1b,  // (2048)
    const float* __restrict__ t2w,
    const float* __restrict__ t2b,
    float* __restrict__ nbb) {
  __shared__ __align__(16) char smem[SMEM_SZ];
  const int t = threadIdx.x;
  const unsigned u = blockIdx.x;
  const int b = (u & 7) | ((u >> 7) << 3);   // XCD-affine: all 16 tiles of b on one XCD
  const int a0 = ((u >> 3) & 15) << 4;
  const int lane = t & 63;
  const int wv = t >> 6;
  const int c16 = lane & 15;
  const int kg = lane >> 4;
  const int l31 = lane & 31;
  const int hi = lane >> 5;

  float* bbs = (float*)(smem + BBS);
  if (t < 192) ((float4*)bbs)[t] = ((const float4*)(bb + b * (L_ * 3)))[t];
  if (t < 256) {
    int row = t >> 4, ch = t & 15;
    uint4 v = *(const uint4*)(xbg + ((size_t)b * L_ + a0 + row) * E_ + ch * 8);
    *(uint4*)(smem + XAS + row * 256 + ((ch ^ row) << 4)) = v;
  }
  __syncthreads();

  // ---- phase 1: x2 tile via 16x16x32, B prefetched from global ----
  {
    bf16x8 a1[4];
#pragma unroll
    for (int kk = 0; kk < 4; ++kk)
      a1[kk] = *(const bf16x8*)(smem + XAS + c16 * 256 + (((kk * 4 + kg) ^ c16) << 4));
    const int ntB = wv * 16;
    bf16x8 cur[4], nxt[4];
    {
      const bfh* bsrc = t1wb + (size_t)(ntB * 16 + c16) * E_ + kg * 8;
#pragma unroll
      for (int kk = 0; kk < 4; ++kk) cur[kk] = *(const bf16x8*)(bsrc + kk * 32);
    }
#pragma unroll
    for (int i = 0; i < 16; ++i) {
      const int nt = ntB + i;
      if (i < 15) {
        const bfh* bsrc = t1wb + (size_t)((nt + 1) * 16 + c16) * E_ + kg * 8;
#pragma unroll
        for (int kk = 0; kk < 4; ++kk) nxt[kk] = *(const bf16x8*)(bsrc + kk * 32);
      }
      f32x4 acc = {0.f, 0.f, 0.f, 0.f};
#pragma unroll
      for (int kk = 0; kk < 4; ++kk)
        acc = __builtin_amdgcn_mfma_f32_16x16x32_bf16(a1[kk], cur[kk], acc, 0, 0, 0);
      const float bias = t1b[nt * 16 + c16];
#pragma unroll
      for (int r = 0; r < 4; ++r) {
        int a = kg * 4 + r;
        int row = (a >> 1) * 32 + ((c16 & 3) | ((a & 1) << 2) | ((c16 >> 2) << 3));
        *(bfh*)(smem + XBIG + row * 256 + (((nt >> 3) ^ SWZ(row)) << 4) + (nt & 7) * 2) =
            (bfh)(acc[r] + bias);
      }
#pragma unroll
      for (int kk = 0; kk < 4; ++kk) cur[kk] = nxt[kk];
    }
  }
  __syncthreads();

  // ---- phase 2a: extract this wave's A-matrix (32 m-rows x 128 e) into registers ----
  bf16x8 afr[8];
#pragma unroll
  for (int kk = 0; kk < 8; ++kk) {
    int row = wv * 32 + l31;
    afr[kk] = *(const bf16x8*)(smem + XBIG + row * 256 + (((kk * 2 + hi) ^ SWZ(row)) << 4));
  }
  __syncthreads();  // all waves done reading x2 -> XBIG reusable

  // ---- phase 2b: stage the whole x frame (256 rows x 256B) into XBIG ----
#pragma unroll
  for (int i = 0; i < 8; ++i) {
    int s = t + i * 512;
    int row = s >> 4, ch = s & 15;
    uint4 v = *(const uint4*)(xbg + ((size_t)b * L_ + row) * E_ + ch * 8);
    *(uint4*)(smem + XBIG + row * 256 + ((ch ^ SWZ(row)) << 4)) = v;
  }
  __syncthreads();

  // ---- phase 2c: d-loop, LDS-fed, no barriers ----
  const int aglob = a0 + 2 * wv + hi;
  const float bax0 = bbs[aglob * 3 + 0];
  const float bax1 = bbs[aglob * 3 + 1];
  const float bax2 = bbs[aglob * 3 + 2];

  float accX[16], accY[16], accZ[16], accS[16];
#pragma unroll
  for (int q = 0; q < 16; ++q) { accX[q] = 0.f; accY[q] = 0.f; accZ[q] = 0.f; accS[q] = 0.f; }

  bf16x8 bcur[8], bnxt[8];
  {
    const int row = l31;
#pragma unroll
    for (int kk = 0; kk < 8; ++kk)
      bcur[kk] = *(const bf16x8*)(smem + XBIG + row * 256 +
                                  (((kk * 2 + hi) ^ SWZ(row)) << 4));
  }
#pragma unroll
  for (int dt = 0; dt < 8; ++dt) {
    if (dt < 7) {
      const int row = (dt + 1) * 32 + l31;
#pragma unroll
      for (int kk = 0; kk < 8; ++kk)
        bnxt[kk] = *(const bf16x8*)(smem + XBIG + row * 256 +
                                    (((kk * 2 + hi) ^ SWZ(row)) << 4));
    }
    f32x16 acc;
#pragma unroll
    for (int q = 0; q < 16; ++q) acc[q] = 0.f;
#pragma unroll
    for (int kk = 0; kk < 8; ++kk)
      acc = __builtin_amdgcn_mfma_f32_32x32x16_bf16(afr[kk], bcur[kk], acc, 0, 0, 0);
    const int d = dt * 32 + l31;
    const float dx = bax0 - bbs[d * 3 + 0];
    const float dy = bax1 - bbs[d * 3 + 1];
    const float dz = bax2 - bbs[d * 3 + 2];
    float mx = acc[0];
#pragma unroll
    for (int q = 1; q < 16; ++q) mx = fmaxf(mx, acc[q]);
    float p[16], S = 0.f;
#pragma unroll
    for (int q = 0; q < 16; ++q) { p[q] = __expf(acc[q] - mx); S += p[q]; }
    const float inv = __builtin_amdgcn_rcpf(S);
#pragma unroll
    for (int q = 0; q < 16; ++q) {
      const float uu = p[q] * inv;
      accS[q] += uu;
      accX[q] = fmaf(uu, dx, accX[q]);
      accY[q] = fmaf(uu, dy, accY[q]);
      accZ[q] = fmaf(uu, dz, accZ[q]);
    }
#pragma unroll
    for (int kk = 0; kk < 8; ++kk) bcur[kk] = bnxt[kk];
  }

  // ---- phase 3: reduce 32 d-lanes via LDS transpose (XBIG dead -> scr) ----
  float* scr = (float*)smem;
  float* red = (float*)(smem + RED);
#pragma unroll
  for (int pass = 0; pass < 2; ++pass) {
    __syncthreads();
#pragma unroll
    for (int c2 = 0; c2 < 8; ++c2) {
      int c = pass * 8 + c2;
      int base = ((wv * 2 + hi) * 8 + c2) * 4;
      scr[(base + 0) * 32 + l31] = accX[c];
      scr[(base + 1) * 32 + l31] = accY[c];
      scr[(base + 2) * 32 + l31] = accZ[c];
      scr[(base + 3) * 32 + l31] = accS[c];
    }
    __syncthreads();
    {
      float v = 0.f;
#pragma unroll
      for (int j = 0; j < 32; ++j) v += scr[t * 32 + ((j + t) & 31)];
      int m = t & 3, c2 = (t >> 2) & 7, hh = (t >> 5) & 1, wp = t >> 6;
      red[((wp * 2 + hh) * 16 + pass * 8 + c2) * 4 + m] = v;
    }
  }
  __syncthreads();

  // ---- phase 4: vd and new_bb ----
  if (t < 48) {
    int a = t / 3, k = t % 3;
    float vd = 0.f;
#pragma unroll
    for (int c = 0; c < C_; ++c) {
      const float* w2 = t2w + (k * C_ + c) * 3;
      const float* rr = red + (a * 16 + c) * 4;
      vd += w2[0] * rr[0] + w2[1] * rr[1] + w2[2] * rr[2] + t2b[k * C_ + c] * rr[3];
    }
    nbb[(size_t)(b * L_ + a0 + a) * 3 + k] = bbs[(a0 + a) * 3 + k] + STEP_ * vd;
  }
}

// ---------------- mse over frames ----------------
__global__ void k_mse(const float* __restrict__ nbb, const float* __restrict__ bb,
                      float* __restrict__ out) {
  const int b = blockIdx.x;
  const int t = threadIdx.x;
  const float* pn = nbb + ((b + 1) * L_ + t) * 3;
  const float* pb = bb + (b * L_ + t) * 3;
  const float dx = pn[0] - pb[0];
  const float dy = pn[1] - pb[1];
  const float dz = pn[2] - pb[2];
  float v = dx * dx + dy * dy + dz * dz;
  for (int o = 32; o > 0; o >>= 1) v += __shfl_down(v, o);
  __shared__ float wsum[4];
  if ((t & 63) == 0) wsum[t >> 6] = v;
  __syncthreads();
  if (t == 0) out[b] = (wsum[0] + wsum[1] + wsum[2] + wsum[3]) * (1.0f / L_);
}

extern "C" void kernel_launch(void* const* d_in, const int* in_sizes, int n_in,
                              void* d_out, int out_size, void* d_ws, size_t ws_size,
                              hipStream_t stream) {
  const int* aa = (const int*)d_in[0];
  const float* bb = (const float*)d_in[1];
  const float* emb = (const float*)d_in[2];
  const float* conv_w = (const float*)d_in[3];
  const float* conv_b = (const float*)d_in[4];
  const float* t1w = (const float*)d_in[5];
  const float* t1b = (const float*)d_in[6];
  const float* t2w = (const float*)d_in[7];
  const float* t2b = (const float*)d_in[8];
  float* out = (float*)d_out;

  char* ws = (char*)d_ws;
  bfh* xA = (bfh*)ws;                          // 4 MB
  bfh* xB = (bfh*)(ws + 4194304);              // 4 MB
  bfh* t1wb = (bfh*)(ws + 8388608);            // 512 KB
  bfh* wT = (bfh*)(ws + 8912896);              // 640 KB
  float* nbb = (float*)(ws + 9568256);         // 192 KB

  k_prep_t1<<<1024, 256, 0, stream>>>(t1w, t1wb);
  k_prep_w<<<(NL_ * K_ * E_ * E_ + 255) / 256, 256, 0, stream>>>(conv_w, wT);
  k_embed<<<B_ * L_ * E_ / 4 / 256, 256, 0, stream>>>(aa, emb, xA);

  for (int i = 0; i < NL_; ++i) {
    const bfh* src = (i & 1) ? xB : xA;
    bfh* dst = (i & 1) ? xA : xB;
    k_conv<<<dim3(L_ / 32, B_), 512, 0, stream>>>(src, wT + (size_t)i * K_ * E_ * E_,
                                                  conv_b + i * E_, dst);
  }

  k_all<<<B_ * 16, 512, 0, stream>>>(xA, bb, t1wb, t1b, t2w, t2b, nbb);

  k_mse<<<B_ - 1, 256, 0, stream>>>(nbb, bb, out);
}

// Round 7
// 196.584 us; speedup vs baseline: 1.2741x; 1.0084x over previous
//
#include <hip/hip_runtime.h>

#define B_ 64
#define L_ 256
#define E_ 128
#define C_ 16
#define K_ 5
#define NL_ 4
#define STEP_ 0.1f

typedef __bf16 bfh;
typedef __attribute__((ext_vector_type(8))) __bf16 bf16x8;
typedef __attribute__((ext_vector_type(4))) float f32x4;
typedef __attribute__((ext_vector_type(16))) float f32x16;

#define SWZ(r) (((r) ^ ((r) >> 4)) & 15)

// ---------------- embedding gather -> (B,L,E) bf16 ----------------
__global__ void k_embed(const int* __restrict__ aa, const float* __restrict__ emb,
                        bfh* __restrict__ x0) {
  int i4 = blockIdx.x * 256 + threadIdx.x;
  if (i4 >= B_ * L_ * E_ / 4) return;
  int e4 = i4 & 31;
  int l = (i4 >> 5) & (L_ - 1);
  int b = i4 >> 13;
  float4 v = *(const float4*)(emb + (size_t)aa[b * L_ + l] * E_ + e4 * 4);
  union { bfh h[4]; uint2 u; } pk;
  pk.h[0] = (bfh)v.x; pk.h[1] = (bfh)v.y; pk.h[2] = (bfh)v.z; pk.h[3] = (bfh)v.w;
  *(uint2*)(x0 + (size_t)(b * L_ + l) * E_ + e4 * 4) = pk.u;
}

// ---------------- conv weights fp32 (o,i,k) -> bf16 wT[lay][k][o][i] ----------------
__global__ void k_prep_w(const float* __restrict__ w, bfh* __restrict__ wT) {
  int i = blockIdx.x * 256 + threadIdx.x;
  if (i >= NL_ * K_ * E_ * E_) return;
  int ii = i & 127;
  int rest = i >> 7;
  int o = rest & 127;
  int rest2 = rest >> 7;
  int k = rest2 % K_;
  int lay = rest2 / K_;
  wT[i] = (bfh)w[(((size_t)lay * E_ + o) * E_ + ii) * K_ + k];
}

// ---------------- t1w fp32 -> bf16 ----------------
__global__ void k_prep_t1(const float* __restrict__ t1w, bfh* __restrict__ t1wb) {
  int i = blockIdx.x * 256 + threadIdx.x;
  if (i < 2048 * 128) t1wb[i] = (bfh)t1w[i];
}

// ---------------- conv layer via MFMA (unchanged from round 6) ----------------
__global__ __launch_bounds__(512, 4) void k_conv(const bfh* __restrict__ xin,
                                                 const bfh* __restrict__ wT,
                                                 const float* __restrict__ bias,
                                                 bfh* __restrict__ xout) {
  __shared__ __align__(16) char hs[36 * 256];
  const int b = blockIdx.y;
  const int lb = blockIdx.x * 32;
  const int t = threadIdx.x;

  for (int s = t; s < 36 * 16; s += 512) {
    int row = s >> 4, ch = s & 15;
    int lp = lb + row - 2;
    uint4 z = {0, 0, 0, 0};
    uint4 v = (lp >= 0 && lp < L_)
                  ? *(const uint4*)(xin + ((size_t)b * L_ + lp) * E_ + ch * 8)
                  : z;
    *(uint4*)(hs + row * 256 + ((ch ^ (row & 7)) << 4)) = v;
  }
  __syncthreads();

  const int wv = t >> 6, lane = t & 63;
  const int c16 = lane & 15, kg = lane >> 4;
  const int msub = wv & 1;
  const int nq = wv >> 1;

#pragma unroll
  for (int ntl = 0; ntl < 2; ++ntl) {
    const int n0 = nq * 32 + ntl * 16;
    f32x4 acc = {0.f, 0.f, 0.f, 0.f};
#pragma unroll
    for (int k = 0; k < K_; ++k) {
      const bfh* bp = wT + ((size_t)(k * E_ + n0 + c16)) * E_ + kg * 8;
      bf16x8 b0 = *(const bf16x8*)(bp);
      bf16x8 b1 = *(const bf16x8*)(bp + 32);
      bf16x8 b2 = *(const bf16x8*)(bp + 64);
      bf16x8 b3 = *(const bf16x8*)(bp + 96);
      const int row = msub * 16 + c16 + k;
      bf16x8 a0 = *(const bf16x8*)(hs + row * 256 + (((0 * 4 + kg) ^ (row & 7)) << 4));
      bf16x8 a1 = *(const bf16x8*)(hs + row * 256 + (((1 * 4 + kg) ^ (row & 7)) << 4));
      bf16x8 a2 = *(const bf16x8*)(hs + row * 256 + (((2 * 4 + kg) ^ (row & 7)) << 4));
      bf16x8 a3 = *(const bf16x8*)(hs + row * 256 + (((3 * 4 + kg) ^ (row & 7)) << 4));
      acc = __builtin_amdgcn_mfma_f32_16x16x32_bf16(a0, b0, acc, 0, 0, 0);
      acc = __builtin_amdgcn_mfma_f32_16x16x32_bf16(a1, b1, acc, 0, 0, 0);
      acc = __builtin_amdgcn_mfma_f32_16x16x32_bf16(a2, b2, acc, 0, 0, 0);
      acc = __builtin_amdgcn_mfma_f32_16x16x32_bf16(a3, b3, acc, 0, 0, 0);
    }
    const int o = n0 + c16;
    const float bo = bias[o];
#pragma unroll
    for (int r = 0; r < 4; ++r) {
      int lrow = msub * 16 + kg * 4 + r;
      int srow = lrow + 2;
      float res = (float)*(const bfh*)(hs + srow * 256 +
                                       (((o >> 3) ^ (srow & 7)) << 4) + (o & 7) * 2);
      float v = acc[r] + res + bo;
      float ex = __expf(2.f * v);
      float th = 1.f - 2.f / (ex + 1.f);
      xout[((size_t)b * L_ + lb + lrow) * E_ + o] = (bfh)th;
    }
  }
}

// ---------------- fused kernel: x2 GEMM + scores + softmax + accumulate + vd ----------------
#define XBIG 0           // 64 KB
#define XAS 65536        //  4 KB
#define BBS 69632        //  3 KB
#define RED 72704        //  4 KB
#define SMEM_SZ 76800

__global__ __launch_bounds__(512, 2) void k_all(
    const bfh* __restrict__ xbg,    // (B,L,E) bf16
    const float* __restrict__ bb,   // (B,L,3)
    const bfh* __restrict__ t1wb,   // (2048,128) bf16
    const float* __restrict__ t1b,  // (2048)
    const float* __restrict__ t2w,
    const float* __restrict__ t2b,
    float* __restrict__ nbb) {
  __shared__ __align__(16) char smem[SMEM_SZ];
  const int t = threadIdx.x;
  const unsigned u = blockIdx.x;
  const int b = (u & 7) | ((u >> 7) << 3);   // XCD-affine
  const int a0 = ((u >> 3) & 15) << 4;
  const int lane = t & 63;
  const int wv = t >> 6;
  const int c16 = lane & 15;
  const int kg = lane >> 4;
  const int l31 = lane & 31;
  const int hi = lane >> 5;

  float* bbs = (float*)(smem + BBS);
  if (t < 192) ((float4*)bbs)[t] = ((const float4*)(bb + b * (L_ * 3)))[t];
  if (t < 256) {
    int row = t >> 4, ch = t & 15;
    uint4 v = *(const uint4*)(xbg + ((size_t)b * L_ + a0 + row) * E_ + ch * 8);
    *(uint4*)(smem + XAS + row * 256 + ((ch ^ row) << 4)) = v;
  }
  __syncthreads();

  // ---- phase 1: x2 tile via 16x16x32, nt-pairs, dual chains, b32 packed scatter ----
  // LDS row layout: row = (a>>1)*32 + (a&1)*16 + c
  {
    bf16x8 a1[4];
#pragma unroll
    for (int kk = 0; kk < 4; ++kk)
      a1[kk] = *(const bf16x8*)(smem + XAS + c16 * 256 + (((kk * 4 + kg) ^ c16) << 4));
    const int ntB = wv * 16;
    float biasv[16];
#pragma unroll
    for (int i = 0; i < 16; ++i) biasv[i] = t1b[(ntB + i) * 16 + c16];

    bf16x8 cur[8], nxt[8];
    {
      const bfh* b0 = t1wb + (size_t)((ntB + 0) * 16 + c16) * E_ + kg * 8;
      const bfh* b1 = t1wb + (size_t)((ntB + 1) * 16 + c16) * E_ + kg * 8;
#pragma unroll
      for (int kk = 0; kk < 4; ++kk) {
        cur[kk] = *(const bf16x8*)(b0 + kk * 32);
        cur[4 + kk] = *(const bf16x8*)(b1 + kk * 32);
      }
    }
#pragma unroll
    for (int ip = 0; ip < 8; ++ip) {
      const int nt0 = ntB + 2 * ip;
      if (ip < 7) {
        const bfh* b0 = t1wb + (size_t)((nt0 + 2) * 16 + c16) * E_ + kg * 8;
        const bfh* b1 = t1wb + (size_t)((nt0 + 3) * 16 + c16) * E_ + kg * 8;
#pragma unroll
        for (int kk = 0; kk < 4; ++kk) {
          nxt[kk] = *(const bf16x8*)(b0 + kk * 32);
          nxt[4 + kk] = *(const bf16x8*)(b1 + kk * 32);
        }
      }
      f32x4 acc0 = {0.f, 0.f, 0.f, 0.f};
      f32x4 acc1 = {0.f, 0.f, 0.f, 0.f};
#pragma unroll
      for (int kk = 0; kk < 4; ++kk) {
        acc0 = __builtin_amdgcn_mfma_f32_16x16x32_bf16(a1[kk], cur[kk], acc0, 0, 0, 0);
        acc1 = __builtin_amdgcn_mfma_f32_16x16x32_bf16(a1[kk], cur[4 + kk], acc1, 0, 0, 0);
      }
      const float bias0 = biasv[2 * ip];
      const float bias1 = biasv[2 * ip + 1];
      const int p = nt0 >> 1;  // column-pair index 0..63 (global, since ntB even)
#pragma unroll
      for (int r = 0; r < 4; ++r) {
        int a = kg * 4 + r;
        int row = (a >> 1) * 32 + (a & 1) * 16 + c16;
        union { bfh h; ushort s; } lo, hi2;
        lo.h = (bfh)(acc0[r] + bias0);
        hi2.h = (bfh)(acc1[r] + bias1);
        unsigned pk = (unsigned)lo.s | ((unsigned)hi2.s << 16);
        *(unsigned*)(smem + XBIG + row * 256 + (((p >> 2) ^ SWZ(row)) << 4) + (p & 3) * 4) = pk;
      }
#pragma unroll
      for (int kk = 0; kk < 8; ++kk) cur[kk] = nxt[kk];
    }
  }
  __syncthreads();

  // ---- phase 2a: extract this wave's A-matrix into registers ----
  bf16x8 afr[8];
  {
    const int m = l31;
    const int cdec = (m & 3) | (((m >> 3) & 3) << 2);
    const int alsb = (m >> 2) & 1;
    const int row = wv * 32 + alsb * 16 + cdec;
#pragma unroll
    for (int kk = 0; kk < 8; ++kk)
      afr[kk] = *(const bf16x8*)(smem + XBIG + row * 256 + (((kk * 2 + hi) ^ SWZ(row)) << 4));
  }
  __syncthreads();  // XBIG reusable

  // ---- phase 2b: stage the whole x frame ----
#pragma unroll
  for (int i = 0; i < 8; ++i) {
    int s = t + i * 512;
    int row = s >> 4, ch = s & 15;
    uint4 v = *(const uint4*)(xbg + ((size_t)b * L_ + row) * E_ + ch * 8);
    *(uint4*)(smem + XBIG + row * 256 + ((ch ^ SWZ(row)) << 4)) = v;
  }
  __syncthreads();

  // ---- phase 2c: d-loop, LDS-fed, no barriers, no-max softmax ----
  const int aglob = a0 + 2 * wv + hi;
  const float bax0 = bbs[aglob * 3 + 0];
  const float bax1 = bbs[aglob * 3 + 1];
  const float bax2 = bbs[aglob * 3 + 2];

  float accX[16], accY[16], accZ[16], accS[16];
#pragma unroll
  for (int q = 0; q < 16; ++q) { accX[q] = 0.f; accY[q] = 0.f; accZ[q] = 0.f; accS[q] = 0.f; }

  bf16x8 bcur[8], bnxt[8];
  {
    const int row = l31;
#pragma unroll
    for (int kk = 0; kk < 8; ++kk)
      bcur[kk] = *(const bf16x8*)(smem + XBIG + row * 256 +
                                  (((kk * 2 + hi) ^ SWZ(row)) << 4));
  }
#pragma unroll
  for (int dt = 0; dt < 8; ++dt) {
    if (dt < 7) {
      const int row = (dt + 1) * 32 + l31;
#pragma unroll
      for (int kk = 0; kk < 8; ++kk)
        bnxt[kk] = *(const bf16x8*)(smem + XBIG + row * 256 +
                                    (((kk * 2 + hi) ^ SWZ(row)) << 4));
    }
    f32x16 acc0, acc1;
#pragma unroll
    for (int q = 0; q < 16; ++q) { acc0[q] = 0.f; acc1[q] = 0.f; }
#pragma unroll
    for (int kk = 0; kk < 4; ++kk) {
      acc0 = __builtin_amdgcn_mfma_f32_32x32x16_bf16(afr[2 * kk], bcur[2 * kk], acc0, 0, 0, 0);
      acc1 = __builtin_amdgcn_mfma_f32_32x32x16_bf16(afr[2 * kk + 1], bcur[2 * kk + 1], acc1, 0, 0, 0);
    }
    const int d = dt * 32 + l31;
    const float dx = bax0 - bbs[d * 3 + 0];
    const float dy = bax1 - bbs[d * 3 + 1];
    const float dz = bax2 - bbs[d * 3 + 2];
    float p[16];
#pragma unroll
    for (int q = 0; q < 16; ++q) p[q] = __expf(acc0[q] + acc1[q]);
    const float s0 = (p[0] + p[1]) + (p[2] + p[3]);
    const float s1 = (p[4] + p[5]) + (p[6] + p[7]);
    const float s2 = (p[8] + p[9]) + (p[10] + p[11]);
    const float s3 = (p[12] + p[13]) + (p[14] + p[15]);
    const float S = (s0 + s1) + (s2 + s3);
    const float inv = __builtin_amdgcn_rcpf(S);
#pragma unroll
    for (int q = 0; q < 16; ++q) {
      const float uu = p[q] * inv;
      accS[q] += uu;
      accX[q] = fmaf(uu, dx, accX[q]);
      accY[q] = fmaf(uu, dy, accY[q]);
      accZ[q] = fmaf(uu, dz, accZ[q]);
    }
#pragma unroll
    for (int kk = 0; kk < 8; ++kk) bcur[kk] = bnxt[kk];
  }

  // ---- phase 3: reduce 32 d-lanes via LDS transpose ----
  float* scr = (float*)smem;
  float* red = (float*)(smem + RED);
#pragma unroll
  for (int pass = 0; pass < 2; ++pass) {
    __syncthreads();
#pragma unroll
    for (int c2 = 0; c2 < 8; ++c2) {
      int c = pass * 8 + c2;
      int base = ((wv * 2 + hi) * 8 + c2) * 4;
      scr[(base + 0) * 32 + l31] = accX[c];
      scr[(base + 1) * 32 + l31] = accY[c];
      scr[(base + 2) * 32 + l31] = accZ[c];
      scr[(base + 3) * 32 + l31] = accS[c];
    }
    __syncthreads();
    {
      float v = 0.f;
#pragma unroll
      for (int j = 0; j < 32; ++j) v += scr[t * 32 + ((j + t) & 31)];
      int m = t & 3, c2 = (t >> 2) & 7, hh = (t >> 5) & 1, wp = t >> 6;
      red[((wp * 2 + hh) * 16 + pass * 8 + c2) * 4 + m] = v;
    }
  }
  __syncthreads();

  // ---- phase 4: vd and new_bb ----
  if (t < 48) {
    int a = t / 3, k = t % 3;
    float vd = 0.f;
#pragma unroll
    for (int c = 0; c < C_; ++c) {
      const float* w2 = t2w + (k * C_ + c) * 3;
      const float* rr = red + (a * 16 + c) * 4;
      vd += w2[0] * rr[0] + w2[1] * rr[1] + w2[2] * rr[2] + t2b[k * C_ + c] * rr[3];
    }
    nbb[(size_t)(b * L_ + a0 + a) * 3 + k] = bbs[(a0 + a) * 3 + k] + STEP_ * vd;
  }
}

// ---------------- mse over frames ----------------
__global__ void k_mse(const float* __restrict__ nbb, const float* __restrict__ bb,
                      float* __restrict__ out) {
  const int b = blockIdx.x;
  const int t = threadIdx.x;
  const float* pn = nbb + ((b + 1) * L_ + t) * 3;
  const float* pb = bb + (b * L_ + t) * 3;
  const float dx = pn[0] - pb[0];
  const float dy = pn[1] - pb[1];
  const float dz = pn[2] - pb[2];
  float v = dx * dx + dy * dy + dz * dz;
  for (int o = 32; o > 0; o >>= 1) v += __shfl_down(v, o);
  __shared__ float wsum[4];
  if ((t & 63) == 0) wsum[t >> 6] = v;
  __syncthreads();
  if (t == 0) out[b] = (wsum[0] + wsum[1] + wsum[2] + wsum[3]) * (1.0f / L_);
}

extern "C" void kernel_launch(void* const* d_in, const int* in_sizes, int n_in,
                              void* d_out, int out_size, void* d_ws, size_t ws_size,
                              hipStream_t stream) {
  const int* aa = (const int*)d_in[0];
  const float* bb = (const float*)d_in[1];
  const float* emb = (const float*)d_in[2];
  const float* conv_w = (const float*)d_in[3];
  const float* conv_b = (const float*)d_in[4];
  const float* t1w = (const float*)d_in[5];
  const float* t1b = (const float*)d_in[6];
  const float* t2w = (const float*)d_in[7];
  const float* t2b = (const float*)d_in[8];
  float* out = (float*)d_out;

  char* ws = (char*)d_ws;
  bfh* xA = (bfh*)ws;                          // 4 MB
  bfh* xB = (bfh*)(ws + 4194304);              // 4 MB
  bfh* t1wb = (bfh*)(ws + 8388608);            // 512 KB
  bfh* wT = (bfh*)(ws + 8912896);              // 640 KB
  float* nbb = (float*)(ws + 9568256);         // 192 KB

  k_prep_t1<<<1024, 256, 0, stream>>>(t1w, t1wb);
  k_prep_w<<<(NL_ * K_ * E_ * E_ + 255) / 256, 256, 0, stream>>>(conv_w, wT);
  k_embed<<<B_ * L_ * E_ / 4 / 256, 256, 0, stream>>>(aa, emb, xA);

  for (int i = 0; i < NL_; ++i) {
    const bfh* src = (i & 1) ? xB : xA;
    bfh* dst = (i & 1) ? xA : xB;
    k_conv<<<dim3(L_ / 32, B_), 512, 0, stream>>>(src, wT + (size_t)i * K_ * E_ * E_,
                                                  conv_b + i * E_, dst);
  }

  k_all<<<B_ * 16, 512, 0, stream>>>(xA, bb, t1wb, t1b, t2w, t2b, nbb);

  k_mse<<<B_ - 1, 256, 0, stream>>>(nbb, bb, out);
}

// Round 8
// 178.242 us; speedup vs baseline: 1.4052x; 1.1029x over previous
//
#include <hip/hip_runtime.h>

#define B_ 64
#define L_ 256
#define E_ 128
#define C_ 16
#define K_ 5
#define NL_ 4
#define STEP_ 0.1f
#define LOG2E_ 1.4426950408889634f

typedef __bf16 bfh;
typedef __attribute__((ext_vector_type(8))) __bf16 bf16x8;
typedef __attribute__((ext_vector_type(4))) float f32x4;
typedef __attribute__((ext_vector_type(16))) float f32x16;

#define SWZ(r) (((r) ^ ((r) >> 4)) & 15)

// ---------------- embedding gather -> (B,L,E) bf16 ----------------
__global__ void k_embed(const int* __restrict__ aa, const float* __restrict__ emb,
                        bfh* __restrict__ x0) {
  int i4 = blockIdx.x * 256 + threadIdx.x;
  if (i4 >= B_ * L_ * E_ / 4) return;
  int e4 = i4 & 31;
  int l = (i4 >> 5) & (L_ - 1);
  int b = i4 >> 13;
  float4 v = *(const float4*)(emb + (size_t)aa[b * L_ + l] * E_ + e4 * 4);
  union { bfh h[4]; uint2 u; } pk;
  pk.h[0] = (bfh)v.x; pk.h[1] = (bfh)v.y; pk.h[2] = (bfh)v.z; pk.h[3] = (bfh)v.w;
  *(uint2*)(x0 + (size_t)(b * L_ + l) * E_ + e4 * 4) = pk.u;
}

// ---------------- conv weights fp32 (o,i,k) -> bf16 wT[lay][k][o][i] ----------------
__global__ void k_prep_w(const float* __restrict__ w, bfh* __restrict__ wT) {
  int i = blockIdx.x * 256 + threadIdx.x;
  if (i >= NL_ * K_ * E_ * E_) return;
  int ii = i & 127;
  int rest = i >> 7;
  int o = rest & 127;
  int rest2 = rest >> 7;
  int k = rest2 % K_;
  int lay = rest2 / K_;
  wT[i] = (bfh)w[(((size_t)lay * E_ + o) * E_ + ii) * K_ + k];
}

// ---------------- t1w fp32 -> bf16, pre-scaled by log2(e) for exp2 softmax ----------------
__global__ void k_prep_t1(const float* __restrict__ t1w, bfh* __restrict__ t1wb) {
  int i = blockIdx.x * 256 + threadIdx.x;
  if (i < 2048 * 128) t1wb[i] = (bfh)(t1w[i] * LOG2E_);
}

// ---------------- conv layer via MFMA (layers 0..2, row-major out) ----------------
__global__ __launch_bounds__(512, 4) void k_conv(const bfh* __restrict__ xin,
                                                 const bfh* __restrict__ wT,
                                                 const float* __restrict__ bias,
                                                 bfh* __restrict__ xout) {
  __shared__ __align__(16) char hs[36 * 256];
  const int b = blockIdx.y;
  const int lb = blockIdx.x * 32;
  const int t = threadIdx.x;

  for (int s = t; s < 36 * 16; s += 512) {
    int row = s >> 4, ch = s & 15;
    int lp = lb + row - 2;
    uint4 z = {0, 0, 0, 0};
    uint4 v = (lp >= 0 && lp < L_)
                  ? *(const uint4*)(xin + ((size_t)b * L_ + lp) * E_ + ch * 8)
                  : z;
    *(uint4*)(hs + row * 256 + ((ch ^ (row & 7)) << 4)) = v;
  }
  __syncthreads();

  const int wv = t >> 6, lane = t & 63;
  const int c16 = lane & 15, kg = lane >> 4;
  const int msub = wv & 1;
  const int nq = wv >> 1;

#pragma unroll
  for (int ntl = 0; ntl < 2; ++ntl) {
    const int n0 = nq * 32 + ntl * 16;
    f32x4 acc = {0.f, 0.f, 0.f, 0.f};
#pragma unroll
    for (int k = 0; k < K_; ++k) {
      const bfh* bp = wT + ((size_t)(k * E_ + n0 + c16)) * E_ + kg * 8;
      bf16x8 b0 = *(const bf16x8*)(bp);
      bf16x8 b1 = *(const bf16x8*)(bp + 32);
      bf16x8 b2 = *(const bf16x8*)(bp + 64);
      bf16x8 b3 = *(const bf16x8*)(bp + 96);
      const int row = msub * 16 + c16 + k;
      bf16x8 a0 = *(const bf16x8*)(hs + row * 256 + (((0 * 4 + kg) ^ (row & 7)) << 4));
      bf16x8 a1 = *(const bf16x8*)(hs + row * 256 + (((1 * 4 + kg) ^ (row & 7)) << 4));
      bf16x8 a2 = *(const bf16x8*)(hs + row * 256 + (((2 * 4 + kg) ^ (row & 7)) << 4));
      bf16x8 a3 = *(const bf16x8*)(hs + row * 256 + (((3 * 4 + kg) ^ (row & 7)) << 4));
      acc = __builtin_amdgcn_mfma_f32_16x16x32_bf16(a0, b0, acc, 0, 0, 0);
      acc = __builtin_amdgcn_mfma_f32_16x16x32_bf16(a1, b1, acc, 0, 0, 0);
      acc = __builtin_amdgcn_mfma_f32_16x16x32_bf16(a2, b2, acc, 0, 0, 0);
      acc = __builtin_amdgcn_mfma_f32_16x16x32_bf16(a3, b3, acc, 0, 0, 0);
    }
    const int o = n0 + c16;
    const float bo = bias[o];
#pragma unroll
    for (int r = 0; r < 4; ++r) {
      int lrow = msub * 16 + kg * 4 + r;
      int srow = lrow + 2;
      float res = (float)*(const bfh*)(hs + srow * 256 +
                                       (((o >> 3) ^ (srow & 7)) << 4) + (o & 7) * 2);
      float v = acc[r] + res + bo;
      float ex = __expf(2.f * v);
      float th = 1.f - 2.f / (ex + 1.f);
      xout[((size_t)b * L_ + lb + lrow) * E_ + o] = (bfh)th;
    }
  }
}

// ---------------- last conv layer: output in B-frag layout xTg[b][dt][kk][hi][l31][8] ----------------
__global__ __launch_bounds__(512, 4) void k_conv_last(const bfh* __restrict__ xin,
                                                      const bfh* __restrict__ wT,
                                                      const float* __restrict__ bias,
                                                      bfh* __restrict__ xTg) {
  __shared__ __align__(16) char hs[36 * 256];
  const int b = blockIdx.y;
  const int lb = blockIdx.x * 32;
  const int dt = blockIdx.x;  // l-tile == dt tile
  const int t = threadIdx.x;

  for (int s = t; s < 36 * 16; s += 512) {
    int row = s >> 4, ch = s & 15;
    int lp = lb + row - 2;
    uint4 z = {0, 0, 0, 0};
    uint4 v = (lp >= 0 && lp < L_)
                  ? *(const uint4*)(xin + ((size_t)b * L_ + lp) * E_ + ch * 8)
                  : z;
    *(uint4*)(hs + row * 256 + ((ch ^ (row & 7)) << 4)) = v;
  }
  __syncthreads();

  const int wv = t >> 6, lane = t & 63;
  const int c16 = lane & 15, kg = lane >> 4;
  const int msub = wv & 1;
  const int nq = wv >> 1;

#pragma unroll
  for (int ntl = 0; ntl < 2; ++ntl) {
    const int n0 = nq * 32 + ntl * 16;
    f32x4 acc = {0.f, 0.f, 0.f, 0.f};
#pragma unroll
    for (int k = 0; k < K_; ++k) {
      const bfh* bp = wT + ((size_t)(k * E_ + n0 + c16)) * E_ + kg * 8;
      bf16x8 b0 = *(const bf16x8*)(bp);
      bf16x8 b1 = *(const bf16x8*)(bp + 32);
      bf16x8 b2 = *(const bf16x8*)(bp + 64);
      bf16x8 b3 = *(const bf16x8*)(bp + 96);
      const int row = msub * 16 + c16 + k;
      bf16x8 a0 = *(const bf16x8*)(hs + row * 256 + (((0 * 4 + kg) ^ (row & 7)) << 4));
      bf16x8 a1 = *(const bf16x8*)(hs + row * 256 + (((1 * 4 + kg) ^ (row & 7)) << 4));
      bf16x8 a2 = *(const bf16x8*)(hs + row * 256 + (((2 * 4 + kg) ^ (row & 7)) << 4));
      bf16x8 a3 = *(const bf16x8*)(hs + row * 256 + (((3 * 4 + kg) ^ (row & 7)) << 4));
      acc = __builtin_amdgcn_mfma_f32_16x16x32_bf16(a0, b0, acc, 0, 0, 0);
      acc = __builtin_amdgcn_mfma_f32_16x16x32_bf16(a1, b1, acc, 0, 0, 0);
      acc = __builtin_amdgcn_mfma_f32_16x16x32_bf16(a2, b2, acc, 0, 0, 0);
      acc = __builtin_amdgcn_mfma_f32_16x16x32_bf16(a3, b3, acc, 0, 0, 0);
    }
    const int o = n0 + c16;
    const int kkp = nq * 2 + ntl;     // o>>4
    const int hic = c16 >> 3;         // (o>>3)&1
    const int e7 = c16 & 7;           // o&7
    const float bo = bias[o];
#pragma unroll
    for (int r = 0; r < 4; ++r) {
      int lrow = msub * 16 + kg * 4 + r;  // = l31
      int srow = lrow + 2;
      float res = (float)*(const bfh*)(hs + srow * 256 +
                                       (((o >> 3) ^ (srow & 7)) << 4) + (o & 7) * 2);
      float v = acc[r] + res + bo;
      float ex = __expf(2.f * v);
      float th = 1.f - 2.f / (ex + 1.f);
      size_t el = ((((size_t)b * 8 + dt) * 8 + kkp) * 2 + hic) * 256 + lrow * 8 + e7;
      xTg[el] = (bfh)th;
    }
  }
}

// ---------------- x2 GEMM: x2g[b][mblk 128][eo 16][m32 32][8 bf16], frag-ready ----------------
// grid dim3(8, 32): ne = e-16-slice, b_loc = frame in pass. 512 thr. B held in registers.
__global__ __launch_bounds__(512, 2) void k_x2(const bfh* __restrict__ xTg,
                                               const bfh* __restrict__ t1wb,
                                               const float* __restrict__ t1b,
                                               bfh* __restrict__ x2g,
                                               int bBase) {
  __shared__ __align__(16) char smem[65536 + 2 * 8192];
  char* XF = smem;
  const int b_loc = blockIdx.y;
  const int b = bBase + b_loc;
  const int ne = blockIdx.x;
  const int t = threadIdx.x;
  const int wv = t >> 6, lane = t & 63;
  const int c16 = lane & 15, kg = lane >> 4;

  // stage x frame from xTg (frag-layout chunks -> row-major swizzled LDS)
#pragma unroll
  for (int i = 0; i < 8; ++i) {
    int c = t + i * 512;
    int l31 = c & 31, hi5 = (c >> 5) & 1, kk = (c >> 6) & 7, dt = c >> 9;
    int row = dt * 32 + l31;
    int ch = (kk * 2 + hi5) ^ SWZ(row);
    *(uint4*)(XF + row * 256 + (ch << 4)) =
        *(const uint4*)(xTg + (size_t)b * 32768 + (size_t)c * 8);
  }
  __syncthreads();

  // register B-frags: 2 e-columns per wave, reused over all 16 subtiles
  bf16x8 bf[2][4];
  float bias[2];
#pragma unroll
  for (int j = 0; j < 2; ++j) {
    const int e = ne * 16 + wv * 2 + j;
    const int n = e * 16 + c16;
#pragma unroll
    for (int kk = 0; kk < 4; ++kk)
      bf[j][kk] = *(const bf16x8*)(t1wb + (size_t)n * 128 + kk * 32 + kg * 8);
    bias[j] = t1b[n] * LOG2E_;
  }

#pragma unroll 1
  for (int st = 0; st < 16; ++st) {
    char* sc = smem + 65536 + (st & 1) * 8192;
    bf16x8 a1[4];
    const int rowa = st * 16 + c16;
#pragma unroll
    for (int kk = 0; kk < 4; ++kk)
      a1[kk] = *(const bf16x8*)(XF + rowa * 256 + (((kk * 4 + kg) ^ SWZ(rowa)) << 4));
    f32x4 acc0 = {0.f, 0.f, 0.f, 0.f};
    f32x4 acc1 = {0.f, 0.f, 0.f, 0.f};
#pragma unroll
    for (int kk = 0; kk < 4; ++kk) {
      acc0 = __builtin_amdgcn_mfma_f32_16x16x32_bf16(a1[kk], bf[0][kk], acc0, 0, 0, 0);
      acc1 = __builtin_amdgcn_mfma_f32_16x16x32_bf16(a1[kk], bf[1][kk], acc1, 0, 0, 0);
    }
#pragma unroll
    for (int r = 0; r < 4; ++r) {
      int a = kg * 4 + r;
      int m5 = (c16 & 3) | ((a & 1) << 2) | ((c16 >> 2) << 3);
      int row = (a >> 1) * 32 + m5;
      union { bfh h; ushort s; } lo, hi2;
      lo.h = (bfh)(acc0[r] + bias[0]);
      hi2.h = (bfh)(acc1[r] + bias[1]);
      unsigned pk = (unsigned)lo.s | ((unsigned)hi2.s << 16);
      *(unsigned*)(sc + row * 32 + (((wv) ^ ((row >> 2) & 7)) << 2)) = pk;
    }
    __syncthreads();
    // dump subtile (16 a x 16 e) to x2g, coalesced
    {
      const int m32 = t & 31;
      const int eo = (t >> 5) & 1;
      const int mb = t >> 6;
      const int row = mb * 32 + m32;
      uint4 v;
      unsigned* vp = (unsigned*)&v;
#pragma unroll
      for (int jj = 0; jj < 4; ++jj) {
        int j2 = eo * 4 + jj;
        vp[jj] = *(const unsigned*)(sc + row * 32 + ((j2 ^ ((row >> 2) & 7)) << 2));
      }
      size_t el = (((size_t)(b_loc * 128 + st * 8 + mb)) * 16 + ne * 2 + eo) * 256 + m32 * 8;
      *(uint4*)(x2g + el) = v;
    }
  }
}

// ---------------- pairwise kernel: frag loads from global, 1 barrier, no big LDS ----------------
__global__ __launch_bounds__(512, 2) void k_pair(
    const bfh* __restrict__ xTg,    // frag-layout x
    const float* __restrict__ bb,   // (B,L,3)
    const bfh* __restrict__ x2g,    // frag-layout x2 (this pass)
    const float* __restrict__ t2w,
    const float* __restrict__ t2b,
    float* __restrict__ nbb,
    int bBase) {
  __shared__ __align__(16) float bbs[L_ * 3];
  const int t = threadIdx.x;
  const unsigned u = blockIdx.x;
  const int b_loc = (u & 7) | ((u >> 7) << 3);   // XCD-affine within pass
  const int atile = (u >> 3) & 15;
  const int b = bBase + b_loc;
  const int lane = t & 63;
  const int wv = t >> 6;
  const int l31 = lane & 31;
  const int hi = lane >> 5;

  if (t < 192) ((float4*)bbs)[t] = ((const float4*)(bb + b * (L_ * 3)))[t];
  __syncthreads();

  // A-frags: one coalesced load per frag
  bf16x8 afr[8];
  const bfh* abase = x2g + ((size_t)(b_loc * 128 + atile * 8 + wv)) * 4096 + l31 * 8;
#pragma unroll
  for (int kk = 0; kk < 8; ++kk)
    afr[kk] = *(const bf16x8*)(abase + (kk * 2 + hi) * 256);

  const int aglob = atile * 16 + 2 * wv + hi;
  const float bax0 = bbs[aglob * 3 + 0];
  const float bax1 = bbs[aglob * 3 + 1];
  const float bax2 = bbs[aglob * 3 + 2];

  float accX[16], accY[16], accZ[16], accS[16];
#pragma unroll
  for (int q = 0; q < 16; ++q) { accX[q] = 0.f; accY[q] = 0.f; accZ[q] = 0.f; accS[q] = 0.f; }

  const bfh* xb = xTg + (size_t)b * 32768 + hi * 256 + l31 * 8;
  bf16x8 bcur[8], bnxt[8];
#pragma unroll
  for (int kk = 0; kk < 8; ++kk) bcur[kk] = *(const bf16x8*)(xb + kk * 512);

#pragma unroll
  for (int dt = 0; dt < 8; ++dt) {
    if (dt < 7) {
#pragma unroll
      for (int kk = 0; kk < 8; ++kk)
        bnxt[kk] = *(const bf16x8*)(xb + (dt + 1) * 4096 + kk * 512);
    }
    f32x16 acc0, acc1;
#pragma unroll
    for (int q = 0; q < 16; ++q) { acc0[q] = 0.f; acc1[q] = 0.f; }
#pragma unroll
    for (int kk = 0; kk < 4; ++kk) {
      acc0 = __builtin_amdgcn_mfma_f32_32x32x16_bf16(afr[2 * kk], bcur[2 * kk], acc0, 0, 0, 0);
      acc1 = __builtin_amdgcn_mfma_f32_32x32x16_bf16(afr[2 * kk + 1], bcur[2 * kk + 1], acc1, 0, 0, 0);
    }
    const int d = dt * 32 + l31;
    const float dx = bax0 - bbs[d * 3 + 0];
    const float dy = bax1 - bbs[d * 3 + 1];
    const float dz = bax2 - bbs[d * 3 + 2];
    float p[16];
#pragma unroll
    for (int q = 0; q < 16; ++q) p[q] = exp2f(acc0[q] + acc1[q]);
    const float s0 = (p[0] + p[1]) + (p[2] + p[3]);
    const float s1 = (p[4] + p[5]) + (p[6] + p[7]);
    const float s2 = (p[8] + p[9]) + (p[10] + p[11]);
    const float s3 = (p[12] + p[13]) + (p[14] + p[15]);
    const float S = (s0 + s1) + (s2 + s3);
    const float inv = __builtin_amdgcn_rcpf(S);
#pragma unroll
    for (int q = 0; q < 16; ++q) {
      const float uu = p[q] * inv;
      accS[q] += uu;
      accX[q] = fmaf(uu, dx, accX[q]);
      accY[q] = fmaf(uu, dy, accY[q]);
      accZ[q] = fmaf(uu, dz, accZ[q]);
    }
#pragma unroll
    for (int kk = 0; kk < 8; ++kk) bcur[kk] = bnxt[kk];
  }

  // in-thread contraction over c with t2w/t2b, then shuffle-reduce over 32 d-lanes
  float vk[3] = {0.f, 0.f, 0.f};
#pragma unroll
  for (int c = 0; c < 16; ++c) {
#pragma unroll
    for (int k = 0; k < 3; ++k) {
      const float* w2 = t2w + (k * C_ + c) * 3;
      vk[k] += w2[0] * accX[c] + w2[1] * accY[c] + w2[2] * accZ[c] +
               t2b[k * C_ + c] * accS[c];
    }
  }
#pragma unroll
  for (int m = 1; m <= 16; m <<= 1) {
    vk[0] += __shfl_xor(vk[0], m);
    vk[1] += __shfl_xor(vk[1], m);
    vk[2] += __shfl_xor(vk[2], m);
  }
  if (l31 == 0) {
#pragma unroll
    for (int k = 0; k < 3; ++k)
      nbb[(size_t)(b * L_ + aglob) * 3 + k] = bbs[aglob * 3 + k] + STEP_ * vk[k];
  }
}

// ---------------- mse over frames ----------------
__global__ void k_mse(const float* __restrict__ nbb, const float* __restrict__ bb,
                      float* __restrict__ out) {
  const int b = blockIdx.x;
  const int t = threadIdx.x;
  const float* pn = nbb + ((b + 1) * L_ + t) * 3;
  const float* pb = bb + (b * L_ + t) * 3;
  const float dx = pn[0] - pb[0];
  const float dy = pn[1] - pb[1];
  const float dz = pn[2] - pb[2];
  float v = dx * dx + dy * dy + dz * dz;
  for (int o = 32; o > 0; o >>= 1) v += __shfl_down(v, o);
  __shared__ float wsum[4];
  if ((t & 63) == 0) wsum[t >> 6] = v;
  __syncthreads();
  if (t == 0) out[b] = (wsum[0] + wsum[1] + wsum[2] + wsum[3]) * (1.0f / L_);
}

extern "C" void kernel_launch(void* const* d_in, const int* in_sizes, int n_in,
                              void* d_out, int out_size, void* d_ws, size_t ws_size,
                              hipStream_t stream) {
  const int* aa = (const int*)d_in[0];
  const float* bb = (const float*)d_in[1];
  const float* emb = (const float*)d_in[2];
  const float* conv_w = (const float*)d_in[3];
  const float* conv_b = (const float*)d_in[4];
  const float* t1w = (const float*)d_in[5];
  const float* t1b = (const float*)d_in[6];
  const float* t2w = (const float*)d_in[7];
  const float* t2b = (const float*)d_in[8];
  float* out = (float*)d_out;

  char* ws = (char*)d_ws;
  bfh* xA = (bfh*)ws;                           // 4 MB  (B,L,E) row-major
  bfh* xTg = (bfh*)(ws + 4194304);              // 4 MB  frag-layout x
  bfh* t1wb = (bfh*)(ws + 8388608);             // 512 KB
  bfh* wT = (bfh*)(ws + 8912896);               // 640 KB
  float* nbb = (float*)(ws + 9568256);          // 192 KB
  bfh* x2g = (bfh*)(ws + 10485760);             // 32 MB per-pass frag-layout x2
  bfh* xB = (bfh*)(ws + 10485760);              // aliases x2g (dead before k_x2)

  k_prep_t1<<<1024, 256, 0, stream>>>(t1w, t1wb);
  k_prep_w<<<(NL_ * K_ * E_ * E_ + 255) / 256, 256, 0, stream>>>(conv_w, wT);
  k_embed<<<B_ * L_ * E_ / 4 / 256, 256, 0, stream>>>(aa, emb, xA);

  // conv stack: xA -> xB -> xA -> xB -> xTg (frag layout)
  k_conv<<<dim3(L_ / 32, B_), 512, 0, stream>>>(xA, wT + (size_t)0 * K_ * E_ * E_,
                                                conv_b + 0 * E_, xB);
  k_conv<<<dim3(L_ / 32, B_), 512, 0, stream>>>(xB, wT + (size_t)1 * K_ * E_ * E_,
                                                conv_b + 1 * E_, xA);
  k_conv<<<dim3(L_ / 32, B_), 512, 0, stream>>>(xA, wT + (size_t)2 * K_ * E_ * E_,
                                                conv_b + 2 * E_, xB);
  k_conv_last<<<dim3(L_ / 32, B_), 512, 0, stream>>>(xB, wT + (size_t)3 * K_ * E_ * E_,
                                                     conv_b + 3 * E_, xTg);

  for (int pass = 0; pass < 2; ++pass) {
    const int bBase = pass * 32;
    k_x2<<<dim3(8, 32), 512, 0, stream>>>(xTg, t1wb, t1b, x2g, bBase);
    k_pair<<<512, 512, 0, stream>>>(xTg, bb, x2g, t2w, t2b, nbb, bBase);
  }

  k_mse<<<B_ - 1, 256, 0, stream>>>(nbb, bb, out);
}

// Round 9
// 163.173 us; speedup vs baseline: 1.5349x; 1.0924x over previous
//
#include <hip/hip_runtime.h>

#define B_ 64
#define L_ 256
#define E_ 128
#define C_ 16
#define K_ 5
#define NL_ 4
#define STEP_ 0.1f
#define LOG2E_ 1.4426950408889634f

typedef __bf16 bfh;
typedef __attribute__((ext_vector_type(8))) __bf16 bf16x8;
typedef __attribute__((ext_vector_type(4))) float f32x4;
typedef __attribute__((ext_vector_type(16))) float f32x16;

#define SWZ(r) (((r) ^ ((r) >> 4)) & 15)

// ---------------- conv weights fp32 (o,i,k) -> bf16 wT[lay][k][o][i] ----------------
__global__ void k_prep_w(const float* __restrict__ w, bfh* __restrict__ wT) {
  int i = blockIdx.x * 256 + threadIdx.x;
  if (i >= NL_ * K_ * E_ * E_) return;
  int ii = i & 127;
  int rest = i >> 7;
  int o = rest & 127;
  int rest2 = rest >> 7;
  int k = rest2 % K_;
  int lay = rest2 / K_;
  wT[i] = (bfh)w[(((size_t)lay * E_ + o) * E_ + ii) * K_ + k];
}

// ---------------- t1w fp32 -> bf16, pre-scaled by log2(e) for exp2 softmax ----------------
__global__ void k_prep_t1(const float* __restrict__ t1w, bfh* __restrict__ t1wb) {
  int i = blockIdx.x * 256 + threadIdx.x;
  if (i < 2048 * 128) t1wb[i] = (bfh)(t1w[i] * LOG2E_);
}

// ---------------- conv layer 0: embedding gather fused, row-major out ----------------
__global__ __launch_bounds__(512, 4) void k_conv0(const int* __restrict__ aa,
                                                  const float* __restrict__ emb,
                                                  const bfh* __restrict__ wT,
                                                  const float* __restrict__ bias,
                                                  bfh* __restrict__ xout) {
  __shared__ __align__(16) char hs[36 * 256];
  const int b = blockIdx.y;
  const int lb = blockIdx.x * 32;
  const int t = threadIdx.x;

  for (int s = t; s < 36 * 16; s += 512) {
    int row = s >> 4, ch = s & 15;
    int lp = lb + row - 2;
    uint4 pk = {0, 0, 0, 0};
    if (lp >= 0 && lp < L_) {
      int idx = aa[b * L_ + lp];
      float4 f0 = *(const float4*)(emb + (size_t)idx * E_ + ch * 8);
      float4 f1 = *(const float4*)(emb + (size_t)idx * E_ + ch * 8 + 4);
      union { bfh h[8]; uint4 u; } cv;
      cv.h[0] = (bfh)f0.x; cv.h[1] = (bfh)f0.y; cv.h[2] = (bfh)f0.z; cv.h[3] = (bfh)f0.w;
      cv.h[4] = (bfh)f1.x; cv.h[5] = (bfh)f1.y; cv.h[6] = (bfh)f1.z; cv.h[7] = (bfh)f1.w;
      pk = cv.u;
    }
    *(uint4*)(hs + row * 256 + ((ch ^ (row & 7)) << 4)) = pk;
  }
  __syncthreads();

  const int wv = t >> 6, lane = t & 63;
  const int c16 = lane & 15, kg = lane >> 4;
  const int msub = wv & 1;
  const int nq = wv >> 1;

#pragma unroll
  for (int ntl = 0; ntl < 2; ++ntl) {
    const int n0 = nq * 32 + ntl * 16;
    f32x4 acc = {0.f, 0.f, 0.f, 0.f};
#pragma unroll
    for (int k = 0; k < K_; ++k) {
      const bfh* bp = wT + ((size_t)(k * E_ + n0 + c16)) * E_ + kg * 8;
      bf16x8 b0 = *(const bf16x8*)(bp);
      bf16x8 b1 = *(const bf16x8*)(bp + 32);
      bf16x8 b2 = *(const bf16x8*)(bp + 64);
      bf16x8 b3 = *(const bf16x8*)(bp + 96);
      const int row = msub * 16 + c16 + k;
      bf16x8 a0 = *(const bf16x8*)(hs + row * 256 + (((0 * 4 + kg) ^ (row & 7)) << 4));
      bf16x8 a1 = *(const bf16x8*)(hs + row * 256 + (((1 * 4 + kg) ^ (row & 7)) << 4));
      bf16x8 a2 = *(const bf16x8*)(hs + row * 256 + (((2 * 4 + kg) ^ (row & 7)) << 4));
      bf16x8 a3 = *(const bf16x8*)(hs + row * 256 + (((3 * 4 + kg) ^ (row & 7)) << 4));
      acc = __builtin_amdgcn_mfma_f32_16x16x32_bf16(a0, b0, acc, 0, 0, 0);
      acc = __builtin_amdgcn_mfma_f32_16x16x32_bf16(a1, b1, acc, 0, 0, 0);
      acc = __builtin_amdgcn_mfma_f32_16x16x32_bf16(a2, b2, acc, 0, 0, 0);
      acc = __builtin_amdgcn_mfma_f32_16x16x32_bf16(a3, b3, acc, 0, 0, 0);
    }
    const int o = n0 + c16;
    const float bo = bias[o];
#pragma unroll
    for (int r = 0; r < 4; ++r) {
      int lrow = msub * 16 + kg * 4 + r;
      int srow = lrow + 2;
      float res = (float)*(const bfh*)(hs + srow * 256 +
                                       (((o >> 3) ^ (srow & 7)) << 4) + (o & 7) * 2);
      float v = acc[r] + res + bo;
      float ex = __expf(2.f * v);
      float th = 1.f - 2.f / (ex + 1.f);
      xout[((size_t)b * L_ + lb + lrow) * E_ + o] = (bfh)th;
    }
  }
}

// ---------------- conv layers 1..2, row-major out ----------------
__global__ __launch_bounds__(512, 4) void k_conv(const bfh* __restrict__ xin,
                                                 const bfh* __restrict__ wT,
                                                 const float* __restrict__ bias,
                                                 bfh* __restrict__ xout) {
  __shared__ __align__(16) char hs[36 * 256];
  const int b = blockIdx.y;
  const int lb = blockIdx.x * 32;
  const int t = threadIdx.x;

  for (int s = t; s < 36 * 16; s += 512) {
    int row = s >> 4, ch = s & 15;
    int lp = lb + row - 2;
    uint4 z = {0, 0, 0, 0};
    uint4 v = (lp >= 0 && lp < L_)
                  ? *(const uint4*)(xin + ((size_t)b * L_ + lp) * E_ + ch * 8)
                  : z;
    *(uint4*)(hs + row * 256 + ((ch ^ (row & 7)) << 4)) = v;
  }
  __syncthreads();

  const int wv = t >> 6, lane = t & 63;
  const int c16 = lane & 15, kg = lane >> 4;
  const int msub = wv & 1;
  const int nq = wv >> 1;

#pragma unroll
  for (int ntl = 0; ntl < 2; ++ntl) {
    const int n0 = nq * 32 + ntl * 16;
    f32x4 acc = {0.f, 0.f, 0.f, 0.f};
#pragma unroll
    for (int k = 0; k < K_; ++k) {
      const bfh* bp = wT + ((size_t)(k * E_ + n0 + c16)) * E_ + kg * 8;
      bf16x8 b0 = *(const bf16x8*)(bp);
      bf16x8 b1 = *(const bf16x8*)(bp + 32);
      bf16x8 b2 = *(const bf16x8*)(bp + 64);
      bf16x8 b3 = *(const bf16x8*)(bp + 96);
      const int row = msub * 16 + c16 + k;
      bf16x8 a0 = *(const bf16x8*)(hs + row * 256 + (((0 * 4 + kg) ^ (row & 7)) << 4));
      bf16x8 a1 = *(const bf16x8*)(hs + row * 256 + (((1 * 4 + kg) ^ (row & 7)) << 4));
      bf16x8 a2 = *(const bf16x8*)(hs + row * 256 + (((2 * 4 + kg) ^ (row & 7)) << 4));
      bf16x8 a3 = *(const bf16x8*)(hs + row * 256 + (((3 * 4 + kg) ^ (row & 7)) << 4));
      acc = __builtin_amdgcn_mfma_f32_16x16x32_bf16(a0, b0, acc, 0, 0, 0);
      acc = __builtin_amdgcn_mfma_f32_16x16x32_bf16(a1, b1, acc, 0, 0, 0);
      acc = __builtin_amdgcn_mfma_f32_16x16x32_bf16(a2, b2, acc, 0, 0, 0);
      acc = __builtin_amdgcn_mfma_f32_16x16x32_bf16(a3, b3, acc, 0, 0, 0);
    }
    const int o = n0 + c16;
    const float bo = bias[o];
#pragma unroll
    for (int r = 0; r < 4; ++r) {
      int lrow = msub * 16 + kg * 4 + r;
      int srow = lrow + 2;
      float res = (float)*(const bfh*)(hs + srow * 256 +
                                       (((o >> 3) ^ (srow & 7)) << 4) + (o & 7) * 2);
      float v = acc[r] + res + bo;
      float ex = __expf(2.f * v);
      float th = 1.f - 2.f / (ex + 1.f);
      xout[((size_t)b * L_ + lb + lrow) * E_ + o] = (bfh)th;
    }
  }
}

// ---------------- last conv layer: output in B-frag layout xTg[b][dt][kk][hi][l31][8] ----------------
__global__ __launch_bounds__(512, 4) void k_conv_last(const bfh* __restrict__ xin,
                                                      const bfh* __restrict__ wT,
                                                      const float* __restrict__ bias,
                                                      bfh* __restrict__ xTg) {
  __shared__ __align__(16) char hs[36 * 256];
  const int b = blockIdx.y;
  const int lb = blockIdx.x * 32;
  const int dt = blockIdx.x;
  const int t = threadIdx.x;

  for (int s = t; s < 36 * 16; s += 512) {
    int row = s >> 4, ch = s & 15;
    int lp = lb + row - 2;
    uint4 z = {0, 0, 0, 0};
    uint4 v = (lp >= 0 && lp < L_)
                  ? *(const uint4*)(xin + ((size_t)b * L_ + lp) * E_ + ch * 8)
                  : z;
    *(uint4*)(hs + row * 256 + ((ch ^ (row & 7)) << 4)) = v;
  }
  __syncthreads();

  const int wv = t >> 6, lane = t & 63;
  const int c16 = lane & 15, kg = lane >> 4;
  const int msub = wv & 1;
  const int nq = wv >> 1;

#pragma unroll
  for (int ntl = 0; ntl < 2; ++ntl) {
    const int n0 = nq * 32 + ntl * 16;
    f32x4 acc = {0.f, 0.f, 0.f, 0.f};
#pragma unroll
    for (int k = 0; k < K_; ++k) {
      const bfh* bp = wT + ((size_t)(k * E_ + n0 + c16)) * E_ + kg * 8;
      bf16x8 b0 = *(const bf16x8*)(bp);
      bf16x8 b1 = *(const bf16x8*)(bp + 32);
      bf16x8 b2 = *(const bf16x8*)(bp + 64);
      bf16x8 b3 = *(const bf16x8*)(bp + 96);
      const int row = msub * 16 + c16 + k;
      bf16x8 a0 = *(const bf16x8*)(hs + row * 256 + (((0 * 4 + kg) ^ (row & 7)) << 4));
      bf16x8 a1 = *(const bf16x8*)(hs + row * 256 + (((1 * 4 + kg) ^ (row & 7)) << 4));
      bf16x8 a2 = *(const bf16x8*)(hs + row * 256 + (((2 * 4 + kg) ^ (row & 7)) << 4));
      bf16x8 a3 = *(const bf16x8*)(hs + row * 256 + (((3 * 4 + kg) ^ (row & 7)) << 4));
      acc = __builtin_amdgcn_mfma_f32_16x16x32_bf16(a0, b0, acc, 0, 0, 0);
      acc = __builtin_amdgcn_mfma_f32_16x16x32_bf16(a1, b1, acc, 0, 0, 0);
      acc = __builtin_amdgcn_mfma_f32_16x16x32_bf16(a2, b2, acc, 0, 0, 0);
      acc = __builtin_amdgcn_mfma_f32_16x16x32_bf16(a3, b3, acc, 0, 0, 0);
    }
    const int o = n0 + c16;
    const int kkp = nq * 2 + ntl;
    const int hic = c16 >> 3;
    const int e7 = c16 & 7;
    const float bo = bias[o];
#pragma unroll
    for (int r = 0; r < 4; ++r) {
      int lrow = msub * 16 + kg * 4 + r;
      int srow = lrow + 2;
      float res = (float)*(const bfh*)(hs + srow * 256 +
                                       (((o >> 3) ^ (srow & 7)) << 4) + (o & 7) * 2);
      float v = acc[r] + res + bo;
      float ex = __expf(2.f * v);
      float th = 1.f - 2.f / (ex + 1.f);
      size_t el = ((((size_t)b * 8 + dt) * 8 + kkp) * 2 + hic) * 256 + lrow * 8 + e7;
      xTg[el] = (bfh)th;
    }
  }
}

// ---------------- x2 GEMM: x2g[b_loc][mblk 128][eo 16][m32 32][8 bf16], frag-ready ----------------
__global__ __launch_bounds__(512, 2) void k_x2(const bfh* __restrict__ xTg,
                                               const bfh* __restrict__ t1wb,
                                               const float* __restrict__ t1b,
                                               bfh* __restrict__ x2g,
                                               int bBase) {
  __shared__ __align__(16) char smem[65536 + 2 * 8192];
  char* XF = smem;
  const int b_loc = blockIdx.y;
  const int b = bBase + b_loc;
  const int ne = blockIdx.x;
  const int t = threadIdx.x;
  const int wv = t >> 6, lane = t & 63;
  const int c16 = lane & 15, kg = lane >> 4;

#pragma unroll
  for (int i = 0; i < 8; ++i) {
    int c = t + i * 512;
    int l31 = c & 31, hi5 = (c >> 5) & 1, kk = (c >> 6) & 7, dt = c >> 9;
    int row = dt * 32 + l31;
    int ch = (kk * 2 + hi5) ^ SWZ(row);
    *(uint4*)(XF + row * 256 + (ch << 4)) =
        *(const uint4*)(xTg + (size_t)b * 32768 + (size_t)c * 8);
  }
  __syncthreads();

  bf16x8 bf[2][4];
  float bias[2];
#pragma unroll
  for (int j = 0; j < 2; ++j) {
    const int e = ne * 16 + wv * 2 + j;
    const int n = e * 16 + c16;
#pragma unroll
    for (int kk = 0; kk < 4; ++kk)
      bf[j][kk] = *(const bf16x8*)(t1wb + (size_t)n * 128 + kk * 32 + kg * 8);
    bias[j] = t1b[n] * LOG2E_;
  }

#pragma unroll 1
  for (int st = 0; st < 16; ++st) {
    char* sc = smem + 65536 + (st & 1) * 8192;
    bf16x8 a1[4];
    const int rowa = st * 16 + c16;
#pragma unroll
    for (int kk = 0; kk < 4; ++kk)
      a1[kk] = *(const bf16x8*)(XF + rowa * 256 + (((kk * 4 + kg) ^ SWZ(rowa)) << 4));
    f32x4 acc0 = {0.f, 0.f, 0.f, 0.f};
    f32x4 acc1 = {0.f, 0.f, 0.f, 0.f};
#pragma unroll
    for (int kk = 0; kk < 4; ++kk) {
      acc0 = __builtin_amdgcn_mfma_f32_16x16x32_bf16(a1[kk], bf[0][kk], acc0, 0, 0, 0);
      acc1 = __builtin_amdgcn_mfma_f32_16x16x32_bf16(a1[kk], bf[1][kk], acc1, 0, 0, 0);
    }
#pragma unroll
    for (int r = 0; r < 4; ++r) {
      int a = kg * 4 + r;
      int m5 = (c16 & 3) | ((a & 1) << 2) | ((c16 >> 2) << 3);
      int row = (a >> 1) * 32 + m5;
      union { bfh h; ushort s; } lo, hi2;
      lo.h = (bfh)(acc0[r] + bias[0]);
      hi2.h = (bfh)(acc1[r] + bias[1]);
      unsigned pk = (unsigned)lo.s | ((unsigned)hi2.s << 16);
      *(unsigned*)(sc + row * 32 + (((wv) ^ ((row >> 2) & 7)) << 2)) = pk;
    }
    __syncthreads();
    {
      const int m32 = t & 31;
      const int eo = (t >> 5) & 1;
      const int mb = t >> 6;
      const int row = mb * 32 + m32;
      uint4 v;
      unsigned* vp = (unsigned*)&v;
#pragma unroll
      for (int jj = 0; jj < 4; ++jj) {
        int j2 = eo * 4 + jj;
        vp[jj] = *(const unsigned*)(sc + row * 32 + ((j2 ^ ((row >> 2) & 7)) << 2));
      }
      size_t el = (((size_t)(b_loc * 128 + st * 8 + mb)) * 16 + ne * 2 + eo) * 256 + m32 * 8;
      *(uint4*)(x2g + el) = v;
    }
  }
}

// ---------------- pairwise kernel: frag loads from global, 1 barrier, 3 KB LDS ----------------
__global__ __launch_bounds__(512, 2) void k_pair(
    const bfh* __restrict__ xTg,
    const float* __restrict__ bb,
    const bfh* __restrict__ x2g,
    const float* __restrict__ t2w,
    const float* __restrict__ t2b,
    float* __restrict__ nbb,
    int bBase) {
  __shared__ __align__(16) float bbs[L_ * 3];
  const int t = threadIdx.x;
  const unsigned u = blockIdx.x;
  const int b_loc = (u & 7) | ((u >> 7) << 3);   // XCD-affine
  const int atile = (u >> 3) & 15;
  const int b = bBase + b_loc;
  const int lane = t & 63;
  const int wv = t >> 6;
  const int l31 = lane & 31;
  const int hi = lane >> 5;

  if (t < 192) ((float4*)bbs)[t] = ((const float4*)(bb + b * (L_ * 3)))[t];
  __syncthreads();

  bf16x8 afr[8];
  const bfh* abase = x2g + ((size_t)(b_loc * 128 + atile * 8 + wv)) * 4096 + l31 * 8;
#pragma unroll
  for (int kk = 0; kk < 8; ++kk)
    afr[kk] = *(const bf16x8*)(abase + (kk * 2 + hi) * 256);

  const int aglob = atile * 16 + 2 * wv + hi;
  const float bax0 = bbs[aglob * 3 + 0];
  const float bax1 = bbs[aglob * 3 + 1];
  const float bax2 = bbs[aglob * 3 + 2];

  float accX[16], accY[16], accZ[16], accS[16];
#pragma unroll
  for (int q = 0; q < 16; ++q) { accX[q] = 0.f; accY[q] = 0.f; accZ[q] = 0.f; accS[q] = 0.f; }

  const bfh* xb = xTg + (size_t)b * 32768 + hi * 256 + l31 * 8;
  bf16x8 bcur[8], bnxt[8];
#pragma unroll
  for (int kk = 0; kk < 8; ++kk) bcur[kk] = *(const bf16x8*)(xb + kk * 512);

#pragma unroll
  for (int dt = 0; dt < 8; ++dt) {
    if (dt < 7) {
#pragma unroll
      for (int kk = 0; kk < 8; ++kk)
        bnxt[kk] = *(const bf16x8*)(xb + (dt + 1) * 4096 + kk * 512);
    }
    f32x16 acc0, acc1;
#pragma unroll
    for (int q = 0; q < 16; ++q) { acc0[q] = 0.f; acc1[q] = 0.f; }
#pragma unroll
    for (int kk = 0; kk < 4; ++kk) {
      acc0 = __builtin_amdgcn_mfma_f32_32x32x16_bf16(afr[2 * kk], bcur[2 * kk], acc0, 0, 0, 0);
      acc1 = __builtin_amdgcn_mfma_f32_32x32x16_bf16(afr[2 * kk + 1], bcur[2 * kk + 1], acc1, 0, 0, 0);
    }
    const int d = dt * 32 + l31;
    const float dx = bax0 - bbs[d * 3 + 0];
    const float dy = bax1 - bbs[d * 3 + 1];
    const float dz = bax2 - bbs[d * 3 + 2];
    float p[16];
#pragma unroll
    for (int q = 0; q < 16; ++q) p[q] = exp2f(acc0[q] + acc1[q]);
    const float s0 = (p[0] + p[1]) + (p[2] + p[3]);
    const float s1 = (p[4] + p[5]) + (p[6] + p[7]);
    const float s2 = (p[8] + p[9]) + (p[10] + p[11]);
    const float s3 = (p[12] + p[13]) + (p[14] + p[15]);
    const float S = (s0 + s1) + (s2 + s3);
    const float inv = __builtin_amdgcn_rcpf(S);
#pragma unroll
    for (int q = 0; q < 16; ++q) {
      const float uu = p[q] * inv;
      accS[q] += uu;
      accX[q] = fmaf(uu, dx, accX[q]);
      accY[q] = fmaf(uu, dy, accY[q]);
      accZ[q] = fmaf(uu, dz, accZ[q]);
    }
#pragma unroll
    for (int kk = 0; kk < 8; ++kk) bcur[kk] = bnxt[kk];
  }

  float vk[3] = {0.f, 0.f, 0.f};
#pragma unroll
  for (int c = 0; c < 16; ++c) {
#pragma unroll
    for (int k = 0; k < 3; ++k) {
      const float* w2 = t2w + (k * C_ + c) * 3;
      vk[k] += w2[0] * accX[c] + w2[1] * accY[c] + w2[2] * accZ[c] +
               t2b[k * C_ + c] * accS[c];
    }
  }
#pragma unroll
  for (int m = 1; m <= 16; m <<= 1) {
    vk[0] += __shfl_xor(vk[0], m);
    vk[1] += __shfl_xor(vk[1], m);
    vk[2] += __shfl_xor(vk[2], m);
  }
  if (l31 == 0) {
#pragma unroll
    for (int k = 0; k < 3; ++k)
      nbb[(size_t)(b * L_ + aglob) * 3 + k] = bbs[aglob * 3 + k] + STEP_ * vk[k];
  }
}

// ---------------- mse over frames ----------------
__global__ void k_mse(const float* __restrict__ nbb, const float* __restrict__ bb,
                      float* __restrict__ out) {
  const int b = blockIdx.x;
  const int t = threadIdx.x;
  const float* pn = nbb + ((b + 1) * L_ + t) * 3;
  const float* pb = bb + (b * L_ + t) * 3;
  const float dx = pn[0] - pb[0];
  const float dy = pn[1] - pb[1];
  const float dz = pn[2] - pb[2];
  float v = dx * dx + dy * dy + dz * dz;
  for (int o = 32; o > 0; o >>= 1) v += __shfl_down(v, o);
  __shared__ float wsum[4];
  if ((t & 63) == 0) wsum[t >> 6] = v;
  __syncthreads();
  if (t == 0) out[b] = (wsum[0] + wsum[1] + wsum[2] + wsum[3]) * (1.0f / L_);
}

extern "C" void kernel_launch(void* const* d_in, const int* in_sizes, int n_in,
                              void* d_out, int out_size, void* d_ws, size_t ws_size,
                              hipStream_t stream) {
  const int* aa = (const int*)d_in[0];
  const float* bb = (const float*)d_in[1];
  const float* emb = (const float*)d_in[2];
  const float* conv_w = (const float*)d_in[3];
  const float* conv_b = (const float*)d_in[4];
  const float* t1w = (const float*)d_in[5];
  const float* t1b = (const float*)d_in[6];
  const float* t2w = (const float*)d_in[7];
  const float* t2b = (const float*)d_in[8];
  float* out = (float*)d_out;

  char* ws = (char*)d_ws;
  bfh* xA = (bfh*)ws;                           // 4 MB
  bfh* xTg = (bfh*)(ws + 4194304);              // 4 MB frag-layout x
  bfh* t1wb = (bfh*)(ws + 8388608);             // 512 KB
  bfh* wT = (bfh*)(ws + 8912896);               // 640 KB
  float* nbb = (float*)(ws + 9568256);          // 192 KB
  bfh* x2g = (bfh*)(ws + 10485760);             // 32 or 64 MB frag-layout x2
  bfh* xB = (bfh*)(ws + 10485760);              // aliases x2g (dead before k_x2)

  k_prep_t1<<<1024, 256, 0, stream>>>(t1w, t1wb);
  k_prep_w<<<(NL_ * K_ * E_ * E_ + 255) / 256, 256, 0, stream>>>(conv_w, wT);

  // conv stack: emb -> xB -> xA -> xB -> xTg (frag layout)
  k_conv0<<<dim3(L_ / 32, B_), 512, 0, stream>>>(aa, emb, wT + (size_t)0 * K_ * E_ * E_,
                                                 conv_b + 0 * E_, xB);
  k_conv<<<dim3(L_ / 32, B_), 512, 0, stream>>>(xB, wT + (size_t)1 * K_ * E_ * E_,
                                                conv_b + 1 * E_, xA);
  k_conv<<<dim3(L_ / 32, B_), 512, 0, stream>>>(xA, wT + (size_t)2 * K_ * E_ * E_,
                                                conv_b + 2 * E_, xB);
  k_conv_last<<<dim3(L_ / 32, B_), 512, 0, stream>>>(xB, wT + (size_t)3 * K_ * E_ * E_,
                                                     conv_b + 3 * E_, xTg);

  const size_t need1 = 10485760ull + 67108864ull;  // layout + full 64 MB x2g
  if (ws_size >= need1) {
    k_x2<<<dim3(8, B_), 512, 0, stream>>>(xTg, t1wb, t1b, x2g, 0);
    k_pair<<<B_ * 16, 512, 0, stream>>>(xTg, bb, x2g, t2w, t2b, nbb, 0);
  } else {
    for (int pass = 0; pass < 2; ++pass) {
      const int bBase = pass * 32;
      k_x2<<<dim3(8, 32), 512, 0, stream>>>(xTg, t1wb, t1b, x2g, bBase);
      k_pair<<<512, 512, 0, stream>>>(xTg, bb, x2g, t2w, t2b, nbb, bBase);
    }
  }

  k_mse<<<B_ - 1, 256, 0, stream>>>(nbb, bb, out);
}